// Round 2
// baseline (222.654 us; speedup 1.0000x reference)
//
#include <hip/hip_runtime.h>
#include <hip/hip_bf16.h>
#include <math.h>

typedef unsigned short ushort_t;
typedef __attribute__((ext_vector_type(8))) short bf16x8;
typedef __attribute__((ext_vector_type(4))) float f32x4;

#define MFMA16(a,b,c) __builtin_amdgcn_mfma_f32_16x16x32_bf16(a,b,c,0,0,0)
#define LOG2E 1.44269504088896340736f

typedef unsigned int u32;
typedef __attribute__((address_space(1))) const u32* gp1_t;
typedef __attribute__((address_space(3))) u32* lp3_t;

__device__ __forceinline__ void async_copy16(void* l, const void* g) {
    __builtin_amdgcn_global_load_lds((gp1_t)g, (lp3_t)l, 16, 0, 0);
}

__device__ __forceinline__ ushort_t f2bf(float f) {
    unsigned u = __float_as_uint(f);
    unsigned r = u + 0x7fffu + ((u >> 16) & 1u);
    return (ushort_t)(r >> 16);
}

// ---------------------------------------------------------------- convert
// [x | Wq | Wk | Wv | Wo] fp32 -> bf16 into ws, 8 elems/thread
__global__ __launch_bounds__(256) void cvt_kernel(
    const float* __restrict__ x,  const float* __restrict__ wq,
    const float* __restrict__ wk, const float* __restrict__ wv,
    const float* __restrict__ wo, ushort_t* __restrict__ dst)
{
    size_t base = ((size_t)blockIdx.x * 256 + threadIdx.x) * 8;
    const float* src; size_t off;
    if      (base < 4194304ul) { src = x;  off = base; }
    else if (base < 5242880ul) { src = wq; off = base - 4194304ul; }
    else if (base < 6291456ul) { src = wk; off = base - 5242880ul; }
    else if (base < 7340032ul) { src = wv; off = base - 6291456ul; }
    else                       { src = wo; off = base - 7340032ul; }
    float4 a = *(const float4*)(src + off);
    float4 b = *(const float4*)(src + off + 4);
    struct alignas(16) U8 { ushort_t v[8]; } o;
    o.v[0]=f2bf(a.x); o.v[1]=f2bf(a.y); o.v[2]=f2bf(a.z); o.v[3]=f2bf(a.w);
    o.v[4]=f2bf(b.x); o.v[5]=f2bf(b.y); o.v[6]=f2bf(b.z); o.v[7]=f2bf(b.w);
    *(U8*)(dst + base) = o;
}

// ---------------------------------------------------------------- GEMM
// C[m,n] = sum_k A[m,k]*B[n,k]  (both row-major, K contiguous; M=4096,N=1024,K=1024)
// mode 0: C -> Q layout [bh][s][64] bf16    mode 1: same -> K
// mode 2: C -> V^T layout [bh][d][s] bf16   mode 3: C -> fp32 linear [m][n]
__global__ __launch_bounds__(256) void gemm_bt(
    const ushort_t* __restrict__ A,  const ushort_t* __restrict__ B0,
    const ushort_t* __restrict__ B1, const ushort_t* __restrict__ B2,
    ushort_t* __restrict__ Oq, ushort_t* __restrict__ Ok,
    ushort_t* __restrict__ Ovt, float* __restrict__ Of, int mode_base)
{
    __shared__ ushort_t As[128 * 64];
    __shared__ ushort_t Bs[128 * 64];
    const int t = threadIdx.x, l = t & 63, w = t >> 6;
    const int l4 = l >> 4, lm = l & 15;
    const int wr = w >> 1, wc = w & 1;
    const int n0 = blockIdx.x * 128, m0 = blockIdx.y * 128;
    const int mode = mode_base + blockIdx.z;
    const ushort_t* B = (mode == 1) ? B1 : (mode == 2) ? B2 : B0;

    f32x4 acc[4][4] = {};
    for (int kt = 0; kt < 16; ++kt) {
        const int k0 = kt * 64;
        __syncthreads();
        #pragma unroll
        for (int i = 0; i < 4; ++i) {
            const int row = i * 32 + (t >> 3);
            const int c = (t & 7) ^ (row & 7);       // inverse-swizzled source
            async_copy16((char*)As + i * 4096 + t * 16,
                         A + (size_t)(m0 + row) * 1024 + k0 + c * 8);
            async_copy16((char*)Bs + i * 4096 + t * 16,
                         B + (size_t)(n0 + row) * 1024 + k0 + c * 8);
        }
        __syncthreads();
        #pragma unroll
        for (int ks = 0; ks < 2; ++ks) {
            bf16x8 af[4], bfr[4];
            #pragma unroll
            for (int mi = 0; mi < 4; ++mi) {
                const int row = wr * 64 + mi * 16 + lm;
                const int ch = l4 + 4 * ks;
                af[mi] = *(const bf16x8*)(As + row * 64 + ((ch ^ (row & 7)) << 3));
            }
            #pragma unroll
            for (int ni = 0; ni < 4; ++ni) {
                const int row = wc * 64 + ni * 16 + lm;
                const int ch = l4 + 4 * ks;
                bfr[ni] = *(const bf16x8*)(Bs + row * 64 + ((ch ^ (row & 7)) << 3));
            }
            #pragma unroll
            for (int mi = 0; mi < 4; ++mi)
                #pragma unroll
                for (int ni = 0; ni < 4; ++ni)
                    acc[mi][ni] = MFMA16(af[mi], bfr[ni], acc[mi][ni]);
        }
    }

    const int mb = m0 + wr * 64, nb = n0 + wc * 64;
    if (mode == 3) {
        #pragma unroll
        for (int mi = 0; mi < 4; ++mi)
            #pragma unroll
            for (int ni = 0; ni < 4; ++ni) {
                const int n = nb + ni * 16 + lm;
                const int mr = mb + mi * 16 + l4 * 4;
                #pragma unroll
                for (int r = 0; r < 4; ++r)
                    Of[(size_t)(mr + r) * 1024 + n] = acc[mi][ni][r];
            }
    } else if (mode == 2) {
        #pragma unroll
        for (int mi = 0; mi < 4; ++mi)
            #pragma unroll
            for (int ni = 0; ni < 4; ++ni) {
                const int n = nb + ni * 16 + lm;
                const int m = mb + mi * 16 + l4 * 4;
                const int b = m >> 11, s = m & 2047, h = n >> 6, d = n & 63;
                ushort4 pk;
                pk.x = f2bf(acc[mi][ni][0]); pk.y = f2bf(acc[mi][ni][1]);
                pk.z = f2bf(acc[mi][ni][2]); pk.w = f2bf(acc[mi][ni][3]);
                *(ushort4*)(Ovt + (((size_t)(b * 16 + h) * 64 + d) * 2048 + s)) = pk;
            }
    } else {
        ushort_t* O = (mode == 0) ? Oq : Ok;
        #pragma unroll
        for (int mi = 0; mi < 4; ++mi)
            #pragma unroll
            for (int ni = 0; ni < 4; ++ni) {
                const int n = nb + ni * 16 + lm;
                const int h = n >> 6, d = n & 63;
                #pragma unroll
                for (int r = 0; r < 4; ++r) {
                    const int m = mb + mi * 16 + l4 * 4 + r;
                    const int b = m >> 11, s = m & 2047;
                    O[((size_t)(b * 16 + h) * 2048 + s) * 64 + d] = f2bf(acc[mi][ni][r]);
                }
            }
    }
}

// ---------------------------------------------------------------- attention
// Q,K: [bh][s][64] bf16;  Vt: [bh][d][s] bf16;  Og: [b][s][1024] bf16
// block = 4 waves x 16 q-rows (QBLK=64), KVBLK=64, causal flash.
__global__ __launch_bounds__(256) void attn_kernel(
    const ushort_t* __restrict__ Qg, const ushort_t* __restrict__ Kg,
    const ushort_t* __restrict__ Vtg, ushort_t* __restrict__ Og)
{
    __shared__ ushort_t Ks[64 * 64];
    __shared__ ushort_t Vs[64 * 64];
    __shared__ ushort_t Ps[4 * 16 * 72];   // per-wave [16][72] (pad 64->72)
    const int t = threadIdx.x, l = t & 63, w = t >> 6;
    const int l4 = l >> 4, lm = l & 15;
    const int qt = blockIdx.x, bh = blockIdx.y;
    const int q0 = qt * 64, q0w = q0 + w * 16;

    bf16x8 qf[2];
    {
        const ushort_t* qp = Qg + ((size_t)bh * 2048 + q0w + lm) * 64 + l4 * 8;
        qf[0] = *(const bf16x8*)qp;
        qf[1] = *(const bf16x8*)(qp + 32);
    }
    f32x4 o[4] = {};
    float m_run[4] = {-1e30f, -1e30f, -1e30f, -1e30f};
    float l_run[4] = {0.f, 0.f, 0.f, 0.f};

    const int nkv = (q0 + 64) >> 6;
    for (int kt = 0; kt < nkv; ++kt) {
        const int kv0 = kt * 64;
        __syncthreads();
        #pragma unroll
        for (int i = 0; i < 2; ++i) {
            const int row = i * 32 + (t >> 3);
            const int c = (t & 7) ^ (row & 7);
            async_copy16((char*)Ks + i * 4096 + t * 16,
                         Kg + ((size_t)bh * 2048 + kv0 + row) * 64 + c * 8);
            async_copy16((char*)Vs + i * 4096 + t * 16,
                         Vtg + ((size_t)bh * 64 + row) * 2048 + kv0 + c * 8);
        }
        __syncthreads();

        // S = Q K^T  (16 x 64 per wave)
        f32x4 sf[4] = {};
        #pragma unroll
        for (int ks = 0; ks < 2; ++ks)
            #pragma unroll
            for (int cf = 0; cf < 4; ++cf) {
                const int rowK = cf * 16 + lm;
                const int ch = l4 + 4 * ks;
                bf16x8 kf = *(const bf16x8*)(Ks + rowK * 64 + ((ch ^ (rowK & 7)) << 3));
                sf[cf] = MFMA16(qf[ks], kf, sf[cf]);
            }

        const bool needmask = (kv0 + 63 > q0w);
        float alpha[4];
        #pragma unroll
        for (int r = 0; r < 4; ++r) {
            const int qrow = q0w + l4 * 4 + r;
            float best = -1e30f;
            #pragma unroll
            for (int cf = 0; cf < 4; ++cf) {
                float v = sf[cf][r] * 0.125f;
                if (needmask && (kv0 + cf * 16 + lm > qrow)) v = -30000.f;
                sf[cf][r] = v;
                best = fmaxf(best, v);
            }
            #pragma unroll
            for (int mo = 1; mo < 16; mo <<= 1)
                best = fmaxf(best, __shfl_xor(best, mo));
            const float mn = fmaxf(m_run[r], best);
            alpha[r] = exp2f((m_run[r] - mn) * LOG2E);
            m_run[r] = mn;
            float su = 0.f;
            #pragma unroll
            for (int cf = 0; cf < 4; ++cf) {
                const float p = exp2f((sf[cf][r] - mn) * LOG2E);
                sf[cf][r] = p;
                su += p;
            }
            #pragma unroll
            for (int mo = 1; mo < 16; mo <<= 1)
                su += __shfl_xor(su, mo);
            l_run[r] = l_run[r] * alpha[r] + su;
        }
        #pragma unroll
        for (int df = 0; df < 4; ++df)
            #pragma unroll
            for (int r = 0; r < 4; ++r)
                o[df][r] *= alpha[r];

        // P -> LDS (bf16), re-read as MFMA A-operand
        #pragma unroll
        for (int cf = 0; cf < 4; ++cf)
            #pragma unroll
            for (int r = 0; r < 4; ++r)
                Ps[w * 1152 + (l4 * 4 + r) * 72 + cf * 16 + lm] = f2bf(sf[cf][r]);
        __syncthreads();

        #pragma unroll
        for (int ks = 0; ks < 2; ++ks) {
            bf16x8 pf = *(const bf16x8*)(Ps + w * 1152 + lm * 72 + l4 * 8 + ks * 32);
            #pragma unroll
            for (int df = 0; df < 4; ++df) {
                const int rowV = df * 16 + lm;
                const int ch = l4 + 4 * ks;
                bf16x8 vf = *(const bf16x8*)(Vs + rowV * 64 + ((ch ^ (rowV & 7)) << 3));
                o[df] = MFMA16(pf, vf, o[df]);
            }
        }
    }

    const int b = bh >> 4, h = bh & 15;
    #pragma unroll
    for (int r = 0; r < 4; ++r) {
        const float inv = 1.f / l_run[r];
        const int srow = q0w + l4 * 4 + r;
        #pragma unroll
        for (int df = 0; df < 4; ++df)
            Og[((size_t)(b * 2048 + srow)) * 1024 + h * 64 + df * 16 + lm] =
                f2bf(o[df][r] * inv);
    }
}

// ---------------------------------------------------------------- launch
extern "C" void kernel_launch(void* const* d_in, const int* in_sizes, int n_in,
                              void* d_out, int out_size, void* d_ws, size_t ws_size,
                              hipStream_t stream)
{
    const float* x  = (const float*)d_in[0];
    const float* Wq = (const float*)d_in[1];
    const float* Wk = (const float*)d_in[2];
    const float* Wv = (const float*)d_in[3];
    const float* Wo = (const float*)d_in[4];

    ushort_t* ws  = (ushort_t*)d_ws;
    ushort_t* xb  = ws;                    // 4194304 elems
    ushort_t* wqb = ws + 4194304;          // 1048576
    ushort_t* wkb = ws + 5242880;
    ushort_t* wvb = ws + 6291456;
    ushort_t* wob = ws + 7340032;
    ushort_t* Qw  = ws + 8388608;          // 4194304  [bh][s][64]
    ushort_t* Kw  = ws + 12582912;         // 4194304  [bh][s][64]
    ushort_t* Vtw = ws + 16777216;         // 4194304  [bh][d][s]
    ushort_t* Aow = ws + 20971520;         // 4194304  [b][s][1024]

    cvt_kernel<<<4096, 256, 0, stream>>>(x, Wq, Wk, Wv, Wo, ws);
    gemm_bt<<<dim3(8, 32, 3), 256, 0, stream>>>(xb, wqb, wkb, wvb,
                                                Qw, Kw, Vtw, nullptr, 0);
    attn_kernel<<<dim3(32, 32), 256, 0, stream>>>(Qw, Kw, Vtw, Aow);
    gemm_bt<<<dim3(8, 32, 1), 256, 0, stream>>>(Aow, wob, wob, wob,
                                                nullptr, nullptr, nullptr,
                                                (float*)d_out, 3);
}

// Round 4
// 136.067 us; speedup vs baseline: 1.6364x; 1.6364x over previous
//
#include <hip/hip_runtime.h>
#include <hip/hip_bf16.h>
#include <math.h>

typedef unsigned short ushort_t;
typedef __attribute__((ext_vector_type(8))) short bf16x8;
typedef __attribute__((ext_vector_type(4))) float f32x4;

#define MFMA16(a,b,c) __builtin_amdgcn_mfma_f32_16x16x32_bf16(a,b,c,0,0,0)
#define LOG2E 1.44269504088896340736f

typedef unsigned int u32;
typedef __attribute__((address_space(1))) const u32* gp1_t;
typedef __attribute__((address_space(3))) u32* lp3_t;

__device__ __forceinline__ void async_copy16(void* l, const void* g) {
    __builtin_amdgcn_global_load_lds((gp1_t)g, (lp3_t)l, 16, 0, 0);
}

__device__ __forceinline__ ushort_t f2bf(float f) {
    unsigned u = __float_as_uint(f);
    unsigned r = u + 0x7fffu + ((u >> 16) & 1u);
    return (ushort_t)(r >> 16);
}

// ---------------------------------------------------------------- convert
// [x | Wq | Wk | Wv | Wo] fp32 -> bf16 into ws, 8 elems/thread
__global__ __launch_bounds__(256) void cvt_kernel(
    const float* __restrict__ x,  const float* __restrict__ wq,
    const float* __restrict__ wk, const float* __restrict__ wv,
    const float* __restrict__ wo, ushort_t* __restrict__ dst)
{
    size_t base = ((size_t)blockIdx.x * 256 + threadIdx.x) * 8;
    const float* src; size_t off;
    if      (base < 4194304ul) { src = x;  off = base; }
    else if (base < 5242880ul) { src = wq; off = base - 4194304ul; }
    else if (base < 6291456ul) { src = wk; off = base - 5242880ul; }
    else if (base < 7340032ul) { src = wv; off = base - 6291456ul; }
    else                       { src = wo; off = base - 7340032ul; }
    float4 a = *(const float4*)(src + off);
    float4 b = *(const float4*)(src + off + 4);
    struct alignas(16) U8 { ushort_t v[8]; } o;
    o.v[0]=f2bf(a.x); o.v[1]=f2bf(a.y); o.v[2]=f2bf(a.z); o.v[3]=f2bf(a.w);
    o.v[4]=f2bf(b.x); o.v[5]=f2bf(b.y); o.v[6]=f2bf(b.z); o.v[7]=f2bf(b.w);
    *(U8*)(dst + base) = o;
}

// ---------------------------------------------------------------- GEMM
// C[m,n] = sum_k A[m,k]*B[n,k]  (both row-major, K contiguous; M=4096,N=1024,K=1024)
// mode 0: C -> Q layout [bh][s][64] bf16    mode 1: same -> K
// mode 2: C -> V^T layout [bh][d][s] bf16   mode 3: C -> fp32 linear [m][n]
__global__ __launch_bounds__(256) void gemm_bt(
    const ushort_t* __restrict__ A,  const ushort_t* __restrict__ B0,
    const ushort_t* __restrict__ B1, const ushort_t* __restrict__ B2,
    ushort_t* __restrict__ Oq, ushort_t* __restrict__ Ok,
    ushort_t* __restrict__ Ovt, float* __restrict__ Of, int mode_base)
{
    __shared__ ushort_t As[128 * 64];
    __shared__ ushort_t Bs[128 * 64];
    const int t = threadIdx.x, l = t & 63, w = t >> 6;
    const int l4 = l >> 4, lm = l & 15;
    const int wr = w >> 1, wc = w & 1;
    const int n0 = blockIdx.x * 128, m0 = blockIdx.y * 128;
    const int mode = mode_base + blockIdx.z;
    const ushort_t* B = (mode == 1) ? B1 : (mode == 2) ? B2 : B0;

    f32x4 acc[4][4] = {};
    for (int kt = 0; kt < 16; ++kt) {
        const int k0 = kt * 64;
        __syncthreads();
        #pragma unroll
        for (int i = 0; i < 4; ++i) {
            const int row = i * 32 + (t >> 3);
            const int c = (t & 7) ^ (row & 7);       // inverse-swizzled source
            async_copy16((char*)As + i * 4096 + t * 16,
                         A + (size_t)(m0 + row) * 1024 + k0 + c * 8);
            async_copy16((char*)Bs + i * 4096 + t * 16,
                         B + (size_t)(n0 + row) * 1024 + k0 + c * 8);
        }
        __syncthreads();
        #pragma unroll
        for (int ks = 0; ks < 2; ++ks) {
            bf16x8 af[4], bfr[4];
            #pragma unroll
            for (int mi = 0; mi < 4; ++mi) {
                const int row = wr * 64 + mi * 16 + lm;
                const int ch = l4 + 4 * ks;
                af[mi] = *(const bf16x8*)(As + row * 64 + ((ch ^ (row & 7)) << 3));
            }
            #pragma unroll
            for (int ni = 0; ni < 4; ++ni) {
                const int row = wc * 64 + ni * 16 + lm;
                const int ch = l4 + 4 * ks;
                bfr[ni] = *(const bf16x8*)(Bs + row * 64 + ((ch ^ (row & 7)) << 3));
            }
            #pragma unroll
            for (int mi = 0; mi < 4; ++mi)
                #pragma unroll
                for (int ni = 0; ni < 4; ++ni)
                    acc[mi][ni] = MFMA16(af[mi], bfr[ni], acc[mi][ni]);
        }
    }

    const int mb = m0 + wr * 64, nb = n0 + wc * 64;
    if (mode == 3) {
        #pragma unroll
        for (int mi = 0; mi < 4; ++mi)
            #pragma unroll
            for (int ni = 0; ni < 4; ++ni) {
                const int n = nb + ni * 16 + lm;
                const int mr = mb + mi * 16 + l4 * 4;
                #pragma unroll
                for (int r = 0; r < 4; ++r)
                    Of[(size_t)(mr + r) * 1024 + n] = acc[mi][ni][r];
            }
    } else if (mode == 2) {
        #pragma unroll
        for (int mi = 0; mi < 4; ++mi)
            #pragma unroll
            for (int ni = 0; ni < 4; ++ni) {
                const int n = nb + ni * 16 + lm;
                const int m = mb + mi * 16 + l4 * 4;
                const int b = m >> 11, s = m & 2047, h = n >> 6, d = n & 63;
                ushort4 pk;
                pk.x = f2bf(acc[mi][ni][0]); pk.y = f2bf(acc[mi][ni][1]);
                pk.z = f2bf(acc[mi][ni][2]); pk.w = f2bf(acc[mi][ni][3]);
                *(ushort4*)(Ovt + (((size_t)(b * 16 + h) * 64 + d) * 2048 + s)) = pk;
            }
    } else {
        ushort_t* O = (mode == 0) ? Oq : Ok;
        #pragma unroll
        for (int mi = 0; mi < 4; ++mi)
            #pragma unroll
            for (int ni = 0; ni < 4; ++ni) {
                const int n = nb + ni * 16 + lm;
                const int h = n >> 6, d = n & 63;
                #pragma unroll
                for (int r = 0; r < 4; ++r) {
                    const int m = mb + mi * 16 + l4 * 4 + r;
                    const int b = m >> 11, s = m & 2047;
                    O[((size_t)(b * 16 + h) * 2048 + s) * 64 + d] = f2bf(acc[mi][ni][r]);
                }
            }
    }
}

// ---------------------------------------------------------------- attention
// Q,K: [bh][s][64] bf16;  Vt: [bh][d][s] bf16;  Og: [b][s][1024] bf16
// 4 waves x 16 q-rows (QBLK=64), KVBLK=64, causal flash.
// Swapped QK^T (mfma(K,Q)) -> lane owns one q-row -> lane-local softmax.
// Swapped PV (mfma(Vt,P)). K/V double-buffered, ONE barrier per tile.
__global__ __launch_bounds__(256) void attn_kernel(
    const ushort_t* __restrict__ Qg, const ushort_t* __restrict__ Kg,
    const ushort_t* __restrict__ Vtg, ushort_t* __restrict__ Og)
{
    __shared__ ushort_t Ks[2][64 * 64];
    __shared__ ushort_t Vs[2][64 * 64];
    __shared__ ushort_t Ps[4][16 * 72];   // per-wave [16 q][64 k] pad->72
    const int t = threadIdx.x, l = t & 63, w = t >> 6;
    const int l4 = l >> 4, lm = l & 15;
    const int bh = blockIdx.x;                 // 0..31 (uniform work per y-row)
    const int qt = 31 - (int)blockIdx.y;       // heavy q-tiles dispatch first
    const int q0 = qt * 64, q0w = q0 + w * 16;
    const int qrow = q0w + lm;                 // this lane's q-row

    bf16x8 qf[2];
    {
        const ushort_t* qp = Qg + ((size_t)bh * 2048 + qrow) * 64 + l4 * 8;
        qf[0] = *(const bf16x8*)qp;
        qf[1] = *(const bf16x8*)(qp + 32);
    }
    f32x4 o[4] = {};
    float m_run = -1e30f, l_run = 0.f;

    const int nkv = qt + 1;
    const int srow = t >> 3, scol = t & 7;

    // prologue: stage tile 0 -> buf 0
    #pragma unroll
    for (int i = 0; i < 2; ++i) {
        const int row = i * 32 + srow;
        const int c = scol ^ (row & 7);
        async_copy16((char*)&Ks[0][0] + i * 4096 + t * 16,
                     Kg + ((size_t)bh * 2048 + row) * 64 + c * 8);
        async_copy16((char*)&Vs[0][0] + i * 4096 + t * 16,
                     Vtg + ((size_t)bh * 64 + row) * 2048 + c * 8);
    }
    __syncthreads();

    for (int kt = 0; kt < nkv; ++kt) {
        const int cur = kt & 1;
        const int kv0 = kt * 64;

        if (kt + 1 < nkv) {        // issue next tile's loads BEFORE compute
            const int nv0 = kv0 + 64;
            #pragma unroll
            for (int i = 0; i < 2; ++i) {
                const int row = i * 32 + srow;
                const int c = scol ^ (row & 7);
                async_copy16((char*)&Ks[cur ^ 1][0] + i * 4096 + t * 16,
                             Kg + ((size_t)bh * 2048 + nv0 + row) * 64 + c * 8);
                async_copy16((char*)&Vs[cur ^ 1][0] + i * 4096 + t * 16,
                             Vtg + ((size_t)bh * 64 + row) * 2048 + nv0 + c * 8);
            }
        }

        // S^T = K Q^T : rows = k, cols = q (lane lm owns q-row qrow)
        f32x4 sf[4] = {};
        #pragma unroll
        for (int ks = 0; ks < 2; ++ks)
            #pragma unroll
            for (int cf = 0; cf < 4; ++cf) {
                const int rowK = cf * 16 + lm;
                const int ch = l4 + 4 * ks;
                bf16x8 kf = *(const bf16x8*)(&Ks[cur][0] + rowK * 64 + ((ch ^ (rowK & 7)) << 3));
                sf[cf] = MFMA16(kf, qf[ks], sf[cf]);
            }

        // scale + causal mask + lane-local max
        float tmax = -1e30f;
        const bool needmask = (kv0 + 63 > q0w);
        #pragma unroll
        for (int cf = 0; cf < 4; ++cf)
            #pragma unroll
            for (int r = 0; r < 4; ++r) {
                float v = sf[cf][r] * 0.125f;
                if (needmask && (kv0 + cf * 16 + l4 * 4 + r > qrow)) v = -30000.f;
                sf[cf][r] = v;
                tmax = fmaxf(tmax, v);
            }
        tmax = fmaxf(tmax, __shfl_xor(tmax, 16));
        tmax = fmaxf(tmax, __shfl_xor(tmax, 32));

        // defer-max: only rescale when tile max grew past THR=8
        if (!__all(tmax <= m_run + 8.f)) {
            const float mn = fmaxf(m_run, tmax);
            const float alpha = exp2f((m_run - mn) * LOG2E);
            l_run *= alpha;
            #pragma unroll
            for (int df = 0; df < 4; ++df)
                #pragma unroll
                for (int r = 0; r < 4; ++r)
                    o[df][r] *= alpha;
            m_run = mn;
        }

        // p = exp(s - m_run), lane-local sum, pack to bf16, wave-private LDS
        float su = 0.f;
        #pragma unroll
        for (int cf = 0; cf < 4; ++cf) {
            u32 w0, w1;
            {
                float p0 = exp2f((sf[cf][0] - m_run) * LOG2E);
                float p1 = exp2f((sf[cf][1] - m_run) * LOG2E);
                float p2 = exp2f((sf[cf][2] - m_run) * LOG2E);
                float p3 = exp2f((sf[cf][3] - m_run) * LOG2E);
                su += p0 + p1 + p2 + p3;
                w0 = (u32)f2bf(p0) | ((u32)f2bf(p1) << 16);
                w1 = (u32)f2bf(p2) | ((u32)f2bf(p3) << 16);
            }
            uint2 pkv; pkv.x = w0; pkv.y = w1;
            *(uint2*)&Ps[w][lm * 72 + cf * 16 + l4 * 4] = pkv;
        }
        su += __shfl_xor(su, 16);
        su += __shfl_xor(su, 32);
        l_run += su;

        // O^T = V^T P^T : rows = d, cols = q
        #pragma unroll
        for (int ks = 0; ks < 2; ++ks) {
            bf16x8 pf = *(const bf16x8*)&Ps[w][lm * 72 + ks * 32 + l4 * 8];
            #pragma unroll
            for (int df = 0; df < 4; ++df) {
                const int rowV = df * 16 + lm;
                const int ch = l4 + 4 * ks;
                bf16x8 vf = *(const bf16x8*)(&Vs[cur][0] + rowV * 64 + ((ch ^ (rowV & 7)) << 3));
                o[df] = MFMA16(vf, pf, o[df]);
            }
        }
        __syncthreads();   // waves done with buf[cur]; next tile's loads drained
    }

    const int b = bh >> 4, h = bh & 15;
    const float inv = 1.f / l_run;
    #pragma unroll
    for (int df = 0; df < 4; ++df) {
        ushort4 pk4;
        pk4.x = f2bf(o[df][0] * inv); pk4.y = f2bf(o[df][1] * inv);
        pk4.z = f2bf(o[df][2] * inv); pk4.w = f2bf(o[df][3] * inv);
        *(ushort4*)&Og[((size_t)(b * 2048 + qrow)) * 1024 + h * 64 + df * 16 + l4 * 4] = pk4;
    }
}

// ---------------------------------------------------------------- launch
extern "C" void kernel_launch(void* const* d_in, const int* in_sizes, int n_in,
                              void* d_out, int out_size, void* d_ws, size_t ws_size,
                              hipStream_t stream)
{
    const float* x  = (const float*)d_in[0];
    const float* Wq = (const float*)d_in[1];
    const float* Wk = (const float*)d_in[2];
    const float* Wv = (const float*)d_in[3];
    const float* Wo = (const float*)d_in[4];

    ushort_t* ws  = (ushort_t*)d_ws;
    ushort_t* xb  = ws;                    // 4194304 elems
    ushort_t* wqb = ws + 4194304;          // 1048576
    ushort_t* wkb = ws + 5242880;
    ushort_t* wvb = ws + 6291456;
    ushort_t* wob = ws + 7340032;
    ushort_t* Qw  = ws + 8388608;          // 4194304  [bh][s][64]
    ushort_t* Kw  = ws + 12582912;         // 4194304  [bh][s][64]
    ushort_t* Vtw = ws + 16777216;         // 4194304  [bh][d][s]
    ushort_t* Aow = ws + 20971520;         // 4194304  [b][s][1024]

    cvt_kernel<<<4096, 256, 0, stream>>>(x, Wq, Wk, Wv, Wo, ws);
    gemm_bt<<<dim3(8, 32, 3), 256, 0, stream>>>(xb, wqb, wkb, wvb,
                                                Qw, Kw, Vtw, nullptr, 0);
    attn_kernel<<<dim3(32, 32), 256, 0, stream>>>(Qw, Kw, Vtw, Aow);
    gemm_bt<<<dim3(8, 32, 1), 256, 0, stream>>>(Aow, wob, wob, wob,
                                                nullptr, nullptr, nullptr,
                                                (float*)d_out, 3);
}

// Round 5
// 123.695 us; speedup vs baseline: 1.8000x; 1.1000x over previous
//
#include <hip/hip_runtime.h>
#include <hip/hip_bf16.h>
#include <math.h>

typedef unsigned short ushort_t;
typedef __attribute__((ext_vector_type(8))) short bf16x8;
typedef __attribute__((ext_vector_type(4))) float f32x4;

#define MFMA16(a,b,c) __builtin_amdgcn_mfma_f32_16x16x32_bf16(a,b,c,0,0,0)
#define QSCALE 0.1803368801111204f   /* 0.125 * log2(e) : softmax in base-2 */

typedef unsigned int u32;
typedef __attribute__((address_space(1))) const u32* gp1_t;
typedef __attribute__((address_space(3))) u32* lp3_t;

__device__ __forceinline__ void async_copy16(void* l, const void* g) {
    __builtin_amdgcn_global_load_lds((gp1_t)g, (lp3_t)l, 16, 0, 0);
}

__device__ __forceinline__ ushort_t f2bf(float f) {
    unsigned u = __float_as_uint(f);
    unsigned r = u + 0x7fffu + ((u >> 16) & 1u);
    return (ushort_t)(r >> 16);
}

// ---------------------------------------------------------------- convert
__global__ __launch_bounds__(256) void cvt_kernel(
    const float* __restrict__ x,  const float* __restrict__ wq,
    const float* __restrict__ wk, const float* __restrict__ wv,
    const float* __restrict__ wo, ushort_t* __restrict__ dst)
{
    size_t base = ((size_t)blockIdx.x * 256 + threadIdx.x) * 8;
    const float* src; size_t off;
    if      (base < 4194304ul) { src = x;  off = base; }
    else if (base < 5242880ul) { src = wq; off = base - 4194304ul; }
    else if (base < 6291456ul) { src = wk; off = base - 5242880ul; }
    else if (base < 7340032ul) { src = wv; off = base - 6291456ul; }
    else                       { src = wo; off = base - 7340032ul; }
    float4 a = *(const float4*)(src + off);
    float4 b = *(const float4*)(src + off + 4);
    struct alignas(16) U8 { ushort_t v[8]; } o;
    o.v[0]=f2bf(a.x); o.v[1]=f2bf(a.y); o.v[2]=f2bf(a.z); o.v[3]=f2bf(a.w);
    o.v[4]=f2bf(b.x); o.v[5]=f2bf(b.y); o.v[6]=f2bf(b.z); o.v[7]=f2bf(b.w);
    *(U8*)(dst + base) = o;
}

// ---------------------------------------------------------------- GEMM
// C[m,n] = sum_k A[m,k]*B[n,k]; M=4096,N=1024,K=1024
// mode 0: C*QSCALE -> Q [bh][s][64]   mode 1: C -> K [bh][s][64]
// mode 2: C -> V^T [bh][d][s]         mode 3: C -> fp32 linear [m][n]
__global__ __launch_bounds__(256) void gemm_bt(
    const ushort_t* __restrict__ A,  const ushort_t* __restrict__ B0,
    const ushort_t* __restrict__ B1, const ushort_t* __restrict__ B2,
    ushort_t* __restrict__ Oq, ushort_t* __restrict__ Ok,
    ushort_t* __restrict__ Ovt, float* __restrict__ Of, int mode_base)
{
    __shared__ ushort_t As[128 * 64];
    __shared__ ushort_t Bs[128 * 64];
    const int t = threadIdx.x, l = t & 63, w = t >> 6;
    const int l4 = l >> 4, lm = l & 15;
    const int wr = w >> 1, wc = w & 1;
    const int n0 = blockIdx.x * 128, m0 = blockIdx.y * 128;
    const int mode = mode_base + blockIdx.z;
    const ushort_t* B = (mode == 1) ? B1 : (mode == 2) ? B2 : B0;

    f32x4 acc[4][4] = {};
    for (int kt = 0; kt < 16; ++kt) {
        const int k0 = kt * 64;
        __syncthreads();
        #pragma unroll
        for (int i = 0; i < 4; ++i) {
            const int row = i * 32 + (t >> 3);
            const int c = (t & 7) ^ (row & 7);       // inverse-swizzled source
            async_copy16((char*)As + i * 4096 + t * 16,
                         A + (size_t)(m0 + row) * 1024 + k0 + c * 8);
            async_copy16((char*)Bs + i * 4096 + t * 16,
                         B + (size_t)(n0 + row) * 1024 + k0 + c * 8);
        }
        __syncthreads();
        #pragma unroll
        for (int ks = 0; ks < 2; ++ks) {
            bf16x8 af[4], bfr[4];
            #pragma unroll
            for (int mi = 0; mi < 4; ++mi) {
                const int row = wr * 64 + mi * 16 + lm;
                const int ch = l4 + 4 * ks;
                af[mi] = *(const bf16x8*)(As + row * 64 + ((ch ^ (row & 7)) << 3));
            }
            #pragma unroll
            for (int ni = 0; ni < 4; ++ni) {
                const int row = wc * 64 + ni * 16 + lm;
                const int ch = l4 + 4 * ks;
                bfr[ni] = *(const bf16x8*)(Bs + row * 64 + ((ch ^ (row & 7)) << 3));
            }
            #pragma unroll
            for (int mi = 0; mi < 4; ++mi)
                #pragma unroll
                for (int ni = 0; ni < 4; ++ni)
                    acc[mi][ni] = MFMA16(af[mi], bfr[ni], acc[mi][ni]);
        }
    }

    const int mb = m0 + wr * 64, nb = n0 + wc * 64;
    if (mode == 3) {
        #pragma unroll
        for (int mi = 0; mi < 4; ++mi)
            #pragma unroll
            for (int ni = 0; ni < 4; ++ni) {
                const int n = nb + ni * 16 + lm;
                const int mr = mb + mi * 16 + l4 * 4;
                #pragma unroll
                for (int r = 0; r < 4; ++r)
                    Of[(size_t)(mr + r) * 1024 + n] = acc[mi][ni][r];
            }
    } else if (mode == 2) {
        #pragma unroll
        for (int mi = 0; mi < 4; ++mi)
            #pragma unroll
            for (int ni = 0; ni < 4; ++ni) {
                const int n = nb + ni * 16 + lm;
                const int m = mb + mi * 16 + l4 * 4;
                const int b = m >> 11, s = m & 2047, h = n >> 6, d = n & 63;
                ushort4 pk;
                pk.x = f2bf(acc[mi][ni][0]); pk.y = f2bf(acc[mi][ni][1]);
                pk.z = f2bf(acc[mi][ni][2]); pk.w = f2bf(acc[mi][ni][3]);
                *(ushort4*)(Ovt + (((size_t)(b * 16 + h) * 64 + d) * 2048 + s)) = pk;
            }
    } else {
        ushort_t* O = (mode == 0) ? Oq : Ok;
        const float qs = (mode == 0) ? (float)QSCALE : 1.0f;
        #pragma unroll
        for (int mi = 0; mi < 4; ++mi)
            #pragma unroll
            for (int ni = 0; ni < 4; ++ni) {
                const int n = nb + ni * 16 + lm;
                const int h = n >> 6, d = n & 63;
                #pragma unroll
                for (int r = 0; r < 4; ++r) {
                    const int m = mb + mi * 16 + l4 * 4 + r;
                    const int b = m >> 11, s = m & 2047;
                    O[((size_t)(b * 16 + h) * 2048 + s) * 64 + d] =
                        f2bf(acc[mi][ni][r] * qs);
                }
            }
    }
}

// ---------------------------------------------------------------- attention
// Q pre-scaled by 0.125*log2e -> softmax computed base-2.
// Swapped QK^T / PV; l tracked as a ones-row MFMA accumulator (rides defer-max).
template<bool MASK>
__device__ __forceinline__ void attn_tile(
    const ushort_t* Kbuf, const ushort_t* Vbuf, ushort_t* Pw,
    const bf16x8 (&qf)[2], const bf16x8 ones,
    f32x4 (&o)[4], f32x4& ol, float& m_run,
    int kv0, int qrow, int l4, int lm)
{
    // S^T = K Q^T : lane lm owns q-row, regs span k
    f32x4 sf[4] = {};
    #pragma unroll
    for (int ks = 0; ks < 2; ++ks)
        #pragma unroll
        for (int cf = 0; cf < 4; ++cf) {
            const int rowK = cf * 16 + lm;
            const int ch = l4 + 4 * ks;
            bf16x8 kf = *(const bf16x8*)(Kbuf + rowK * 64 + ((ch ^ (rowK & 7)) << 3));
            sf[cf] = MFMA16(kf, qf[ks], sf[cf]);
        }

    float tmax = -1e30f;
    #pragma unroll
    for (int cf = 0; cf < 4; ++cf)
        #pragma unroll
        for (int r = 0; r < 4; ++r) {
            float v = sf[cf][r];
            if (MASK && (kv0 + cf * 16 + l4 * 4 + r > qrow)) v = -30000.f;
            sf[cf][r] = v;
            tmax = fmaxf(tmax, v);
        }
    tmax = fmaxf(tmax, __shfl_xor(tmax, 16));
    tmax = fmaxf(tmax, __shfl_xor(tmax, 32));

    // defer-max (THR=8 in log2 units -> P bounded by 256)
    if (!__all(tmax <= m_run + 8.f)) {
        const float mn = fmaxf(m_run, tmax);
        const float alpha = __builtin_amdgcn_exp2f(m_run - mn);
        #pragma unroll
        for (int df = 0; df < 4; ++df)
            #pragma unroll
            for (int r = 0; r < 4; ++r)
                o[df][r] *= alpha;
        #pragma unroll
        for (int r = 0; r < 4; ++r) ol[r] *= alpha;
        m_run = mn;
    }

    // P = 2^(s - m), pack pairs (compiler emits v_cvt_pk_bf16_f32)
    #pragma unroll
    for (int cf = 0; cf < 4; ++cf) {
        float p0 = __builtin_amdgcn_exp2f(sf[cf][0] - m_run);
        float p1 = __builtin_amdgcn_exp2f(sf[cf][1] - m_run);
        float p2 = __builtin_amdgcn_exp2f(sf[cf][2] - m_run);
        float p3 = __builtin_amdgcn_exp2f(sf[cf][3] - m_run);
        __hip_bfloat162 b01 = __float22bfloat162_rn(make_float2(p0, p1));
        __hip_bfloat162 b23 = __float22bfloat162_rn(make_float2(p2, p3));
        uint2 pkv;
        __builtin_memcpy(&pkv.x, &b01, 4);
        __builtin_memcpy(&pkv.y, &b23, 4);
        *(uint2*)&Pw[lm * 72 + cf * 16 + l4 * 4] = pkv;
    }

    // O^T += V^T P^T ; ones-row gives the running denominator
    #pragma unroll
    for (int ks = 0; ks < 2; ++ks) {
        bf16x8 pf = *(const bf16x8*)&Pw[lm * 72 + ks * 32 + l4 * 8];
        #pragma unroll
        for (int df = 0; df < 4; ++df) {
            const int rowV = df * 16 + lm;
            const int ch = l4 + 4 * ks;
            bf16x8 vf = *(const bf16x8*)(Vbuf + rowV * 64 + ((ch ^ (rowV & 7)) << 3));
            o[df] = MFMA16(vf, pf, o[df]);
        }
        ol = MFMA16(ones, pf, ol);
    }
}

__global__ __launch_bounds__(256) void attn_kernel(
    const ushort_t* __restrict__ Qg, const ushort_t* __restrict__ Kg,
    const ushort_t* __restrict__ Vtg, ushort_t* __restrict__ Og)
{
    __shared__ ushort_t Ks[2][64 * 64];
    __shared__ ushort_t Vs[2][64 * 64];
    __shared__ ushort_t Ps[4][16 * 72];
    const int t = threadIdx.x, l = t & 63, w = t >> 6;
    const int l4 = l >> 4, lm = l & 15;
    const int bh = blockIdx.x;
    const int qt = 31 - (int)blockIdx.y;        // heavy q-tiles first
    const int q0 = qt * 64, q0w = q0 + w * 16;
    const int qrow = q0w + lm;

    bf16x8 qf[2];
    {
        const ushort_t* qp = Qg + ((size_t)bh * 2048 + qrow) * 64 + l4 * 8;
        qf[0] = *(const bf16x8*)qp;
        qf[1] = *(const bf16x8*)(qp + 32);
    }
    bf16x8 ones;
    #pragma unroll
    for (int i = 0; i < 8; ++i) ones[i] = (short)0x3F80;

    f32x4 o[4] = {};
    f32x4 ol = {};
    float m_run = -1e30f;

    const int nkv = qt + 1, last = nkv - 1;
    const int srow = t >> 3, scol = t & 7;
    const int stg_i = (srow >= 32), stg_row = srow & 31;   // which half, row in half
    const ushort_t* kg0 = Kg + ((size_t)bh * 2048 + srow) * 64 + (scol ^ (srow & 7)) * 8;
    const ushort_t* vg0 = Vtg + ((size_t)bh * 64 + srow) * 2048 + (scol ^ (srow & 7)) * 8;
    (void)stg_i; (void)stg_row;

    // prologue: stage tile 0 -> buf 0
    async_copy16((char*)&Ks[0][0] + t * 16, kg0);
    async_copy16((char*)&Vs[0][0] + t * 16, vg0);
    async_copy16((char*)&Ks[0][0] + 4096 + t * 16, kg0 + 32 * 64);
    async_copy16((char*)&Vs[0][0] + 4096 + t * 16, vg0 + 32 * 2048);
    __syncthreads();

    for (int kt = 0; kt < last; ++kt) {
        const int cur = kt & 1;
        const size_t koff = (size_t)(kt + 1) * 64 * 64;   // next K tile offset
        const size_t voff = (size_t)(kt + 1) * 64;        // next V^T col offset
        async_copy16((char*)&Ks[cur ^ 1][0] + t * 16, kg0 + koff);
        async_copy16((char*)&Vs[cur ^ 1][0] + t * 16, vg0 + voff);
        async_copy16((char*)&Ks[cur ^ 1][0] + 4096 + t * 16, kg0 + koff + 32 * 64);
        async_copy16((char*)&Vs[cur ^ 1][0] + 4096 + t * 16, vg0 + voff + 32 * 2048);

        attn_tile<false>(&Ks[cur][0], &Vs[cur][0], &Ps[w][0],
                         qf, ones, o, ol, m_run, kt * 64, qrow, l4, lm);
        __syncthreads();
    }
    attn_tile<true>(&Ks[last & 1][0], &Vs[last & 1][0], &Ps[w][0],
                    qf, ones, o, ol, m_run, last * 64, qrow, l4, lm);

    const int b = bh >> 4, h = bh & 15;
    const float inv = 1.f / ol[0];
    #pragma unroll
    for (int df = 0; df < 4; ++df) {
        ushort4 pk4;
        pk4.x = f2bf(o[df][0] * inv); pk4.y = f2bf(o[df][1] * inv);
        pk4.z = f2bf(o[df][2] * inv); pk4.w = f2bf(o[df][3] * inv);
        *(ushort4*)&Og[((size_t)(b * 2048 + qrow)) * 1024 + h * 64 + df * 16 + l4 * 4] = pk4;
    }
}

// ---------------------------------------------------------------- launch
extern "C" void kernel_launch(void* const* d_in, const int* in_sizes, int n_in,
                              void* d_out, int out_size, void* d_ws, size_t ws_size,
                              hipStream_t stream)
{
    const float* x  = (const float*)d_in[0];
    const float* Wq = (const float*)d_in[1];
    const float* Wk = (const float*)d_in[2];
    const float* Wv = (const float*)d_in[3];
    const float* Wo = (const float*)d_in[4];

    ushort_t* ws  = (ushort_t*)d_ws;
    ushort_t* xb  = ws;
    ushort_t* wqb = ws + 4194304;
    ushort_t* wkb = ws + 5242880;
    ushort_t* wvb = ws + 6291456;
    ushort_t* wob = ws + 7340032;
    ushort_t* Qw  = ws + 8388608;          // [bh][s][64] (pre-scaled)
    ushort_t* Kw  = ws + 12582912;         // [bh][s][64]
    ushort_t* Vtw = ws + 16777216;         // [bh][d][s]
    ushort_t* Aow = ws + 20971520;         // [b][s][1024]

    cvt_kernel<<<4096, 256, 0, stream>>>(x, Wq, Wk, Wv, Wo, ws);
    gemm_bt<<<dim3(8, 32, 3), 256, 0, stream>>>(xb, wqb, wkb, wvb,
                                                Qw, Kw, Vtw, nullptr, 0);
    attn_kernel<<<dim3(32, 32), 256, 0, stream>>>(Qw, Kw, Vtw, Aow);
    gemm_bt<<<dim3(8, 32, 1), 256, 0, stream>>>(Aow, wob, wob, wob,
                                                nullptr, nullptr, nullptr,
                                                (float*)d_out, 3);
}

// Round 6
// 120.214 us; speedup vs baseline: 1.8521x; 1.0290x over previous
//
#include <hip/hip_runtime.h>
#include <hip/hip_bf16.h>
#include <math.h>

typedef unsigned short ushort_t;
typedef __attribute__((ext_vector_type(8))) short bf16x8;
typedef __attribute__((ext_vector_type(4))) float f32x4;

#define MFMA16(a,b,c) __builtin_amdgcn_mfma_f32_16x16x32_bf16(a,b,c,0,0,0)
#define QSCALE 0.1803368801111204f   /* 0.125 * log2(e) : softmax in base-2 */

typedef unsigned int u32;
typedef __attribute__((address_space(1))) const u32* gp1_t;
typedef __attribute__((address_space(3))) u32* lp3_t;

__device__ __forceinline__ void async_copy16(void* l, const void* g) {
    __builtin_amdgcn_global_load_lds((gp1_t)g, (lp3_t)l, 16, 0, 0);
}

__device__ __forceinline__ ushort_t f2bf(float f) {
    unsigned u = __float_as_uint(f);
    unsigned r = u + 0x7fffu + ((u >> 16) & 1u);
    return (ushort_t)(r >> 16);
}

// ---------------------------------------------------------------- convert
__global__ __launch_bounds__(256) void cvt_kernel(
    const float* __restrict__ x,  const float* __restrict__ wq,
    const float* __restrict__ wk, const float* __restrict__ wv,
    const float* __restrict__ wo, ushort_t* __restrict__ dst)
{
    size_t base = ((size_t)blockIdx.x * 256 + threadIdx.x) * 8;
    const float* src; size_t off;
    if      (base < 4194304ul) { src = x;  off = base; }
    else if (base < 5242880ul) { src = wq; off = base - 4194304ul; }
    else if (base < 6291456ul) { src = wk; off = base - 5242880ul; }
    else if (base < 7340032ul) { src = wv; off = base - 6291456ul; }
    else                       { src = wo; off = base - 7340032ul; }
    float4 a = *(const float4*)(src + off);
    float4 b = *(const float4*)(src + off + 4);
    struct alignas(16) U8 { ushort_t v[8]; } o;
    o.v[0]=f2bf(a.x); o.v[1]=f2bf(a.y); o.v[2]=f2bf(a.z); o.v[3]=f2bf(a.w);
    o.v[4]=f2bf(b.x); o.v[5]=f2bf(b.y); o.v[6]=f2bf(b.z); o.v[7]=f2bf(b.w);
    *(U8*)(dst + base) = o;
}

// ---------------------------------------------------------------- GEMM
// C[m,n] = sum_k A[m,k]*B[n,k]; row-major, K contiguous. M=4096, K=1024.
// is_out=0: B = concat(Wq,Wk,Wv) [3072x1024], grid x=24; epilogue routed by n:
//   n<1024 -> Q*QSCALE [bh][s][64]; <2048 -> K [bh][s][64]; else V^T [bh][d][s]
// is_out=1: B [1024x1024], grid x=8; C -> fp32 [m][n]
// Double-buffered LDS, prefetch-next-then-compute, ONE barrier per K-step.
__global__ __launch_bounds__(256) void gemm_bt(
    const ushort_t* __restrict__ A, const ushort_t* __restrict__ B,
    ushort_t* __restrict__ Oq, ushort_t* __restrict__ Ok,
    ushort_t* __restrict__ Ovt, float* __restrict__ Of, int is_out)
{
    __shared__ ushort_t As[2][128 * 64];
    __shared__ ushort_t Bs[2][128 * 64];
    const int t = threadIdx.x, l = t & 63, w = t >> 6;
    const int l4 = l >> 4, lm = l & 15;
    const int wr = w >> 1, wc = w & 1;

    // XCD-aware bijective swizzle (nwg % 8 == 0 for both grids)
    const int nwg = gridDim.x * gridDim.y;
    const int orig = (int)blockIdx.y * gridDim.x + (int)blockIdx.x;
    const int qq = nwg >> 3;
    const int swz = (orig & 7) * qq + (orig >> 3);
    const int n0 = (swz % gridDim.x) * 128;
    const int m0 = (swz / gridDim.x) * 128;

    const int srow = t >> 3, scol = t & 7;

    f32x4 acc[4][4] = {};

    // prologue: stage K-tile 0 -> buf 0
    #pragma unroll
    for (int i = 0; i < 4; ++i) {
        const int row = i * 32 + srow;
        const int c = scol ^ (row & 7);
        async_copy16((char*)&As[0][0] + i * 4096 + t * 16,
                     A + (size_t)(m0 + row) * 1024 + c * 8);
        async_copy16((char*)&Bs[0][0] + i * 4096 + t * 16,
                     B + (size_t)(n0 + row) * 1024 + c * 8);
    }
    __syncthreads();

    for (int kt = 0; kt < 16; ++kt) {
        const int cur = kt & 1;
        if (kt + 1 < 16) {              // prefetch next tile BEFORE compute
            const int k0 = (kt + 1) * 64;
            #pragma unroll
            for (int i = 0; i < 4; ++i) {
                const int row = i * 32 + srow;
                const int c = scol ^ (row & 7);
                async_copy16((char*)&As[cur ^ 1][0] + i * 4096 + t * 16,
                             A + (size_t)(m0 + row) * 1024 + k0 + c * 8);
                async_copy16((char*)&Bs[cur ^ 1][0] + i * 4096 + t * 16,
                             B + (size_t)(n0 + row) * 1024 + k0 + c * 8);
            }
        }
        #pragma unroll
        for (int ks = 0; ks < 2; ++ks) {
            bf16x8 af[4], bfr[4];
            #pragma unroll
            for (int mi = 0; mi < 4; ++mi) {
                const int row = wr * 64 + mi * 16 + lm;
                const int ch = l4 + 4 * ks;
                af[mi] = *(const bf16x8*)(&As[cur][0] + row * 64 + ((ch ^ (row & 7)) << 3));
            }
            #pragma unroll
            for (int ni = 0; ni < 4; ++ni) {
                const int row = wc * 64 + ni * 16 + lm;
                const int ch = l4 + 4 * ks;
                bfr[ni] = *(const bf16x8*)(&Bs[cur][0] + row * 64 + ((ch ^ (row & 7)) << 3));
            }
            #pragma unroll
            for (int mi = 0; mi < 4; ++mi)
                #pragma unroll
                for (int ni = 0; ni < 4; ++ni)
                    acc[mi][ni] = MFMA16(af[mi], bfr[ni], acc[mi][ni]);
        }
        __syncthreads();   // reads of buf[cur] done; prefetch into buf[cur^1] drained
    }

    const int mb = m0 + wr * 64, nb = n0 + wc * 64;
    if (is_out) {
        #pragma unroll
        for (int mi = 0; mi < 4; ++mi)
            #pragma unroll
            for (int ni = 0; ni < 4; ++ni) {
                const int n = nb + ni * 16 + lm;
                const int mr = mb + mi * 16 + l4 * 4;
                #pragma unroll
                for (int r = 0; r < 4; ++r)
                    Of[(size_t)(mr + r) * 1024 + n] = acc[mi][ni][r];
            }
    } else if (nb >= 2048) {            // V^T region
        #pragma unroll
        for (int mi = 0; mi < 4; ++mi)
            #pragma unroll
            for (int ni = 0; ni < 4; ++ni) {
                const int nv = nb - 2048 + ni * 16 + lm;
                const int m = mb + mi * 16 + l4 * 4;
                const int b = m >> 11, s = m & 2047, h = nv >> 6, d = nv & 63;
                ushort4 pk;
                pk.x = f2bf(acc[mi][ni][0]); pk.y = f2bf(acc[mi][ni][1]);
                pk.z = f2bf(acc[mi][ni][2]); pk.w = f2bf(acc[mi][ni][3]);
                *(ushort4*)(Ovt + (((size_t)(b * 16 + h) * 64 + d) * 2048 + s)) = pk;
            }
    } else {                            // Q (scaled) or K region
        ushort_t* O = (nb < 1024) ? Oq : Ok;
        const float qs = (nb < 1024) ? (float)QSCALE : 1.0f;
        const int nbase = nb & 1023;
        #pragma unroll
        for (int mi = 0; mi < 4; ++mi)
            #pragma unroll
            for (int ni = 0; ni < 4; ++ni) {
                const int n = nbase + ni * 16 + lm;
                const int h = n >> 6, d = n & 63;
                #pragma unroll
                for (int r = 0; r < 4; ++r) {
                    const int m = mb + mi * 16 + l4 * 4 + r;
                    const int b = m >> 11, s = m & 2047;
                    O[((size_t)(b * 16 + h) * 2048 + s) * 64 + d] =
                        f2bf(acc[mi][ni][r] * qs);
                }
            }
    }
}

// ---------------------------------------------------------------- attention
// Q pre-scaled by 0.125*log2e -> softmax computed base-2.
// Swapped QK^T / PV; l tracked as a ones-row MFMA accumulator (rides defer-max).
template<bool MASK>
__device__ __forceinline__ void attn_tile(
    const ushort_t* Kbuf, const ushort_t* Vbuf, ushort_t* Pw,
    const bf16x8 (&qf)[2], const bf16x8 ones,
    f32x4 (&o)[4], f32x4& ol, float& m_run,
    int kv0, int qrow, int l4, int lm)
{
    // S^T = K Q^T : lane lm owns q-row, regs span k
    f32x4 sf[4] = {};
    #pragma unroll
    for (int ks = 0; ks < 2; ++ks)
        #pragma unroll
        for (int cf = 0; cf < 4; ++cf) {
            const int rowK = cf * 16 + lm;
            const int ch = l4 + 4 * ks;
            bf16x8 kf = *(const bf16x8*)(Kbuf + rowK * 64 + ((ch ^ (rowK & 7)) << 3));
            sf[cf] = MFMA16(kf, qf[ks], sf[cf]);
        }

    float tmax = -1e30f;
    #pragma unroll
    for (int cf = 0; cf < 4; ++cf)
        #pragma unroll
        for (int r = 0; r < 4; ++r) {
            float v = sf[cf][r];
            if (MASK && (kv0 + cf * 16 + l4 * 4 + r > qrow)) v = -30000.f;
            sf[cf][r] = v;
            tmax = fmaxf(tmax, v);
        }
    tmax = fmaxf(tmax, __shfl_xor(tmax, 16));
    tmax = fmaxf(tmax, __shfl_xor(tmax, 32));

    // defer-max (THR=8 in log2 units -> P bounded by 256)
    if (!__all(tmax <= m_run + 8.f)) {
        const float mn = fmaxf(m_run, tmax);
        const float alpha = __builtin_amdgcn_exp2f(m_run - mn);
        #pragma unroll
        for (int df = 0; df < 4; ++df)
            #pragma unroll
            for (int r = 0; r < 4; ++r)
                o[df][r] *= alpha;
        #pragma unroll
        for (int r = 0; r < 4; ++r) ol[r] *= alpha;
        m_run = mn;
    }

    // P = 2^(s - m), pack pairs (compiler emits v_cvt_pk_bf16_f32)
    #pragma unroll
    for (int cf = 0; cf < 4; ++cf) {
        float p0 = __builtin_amdgcn_exp2f(sf[cf][0] - m_run);
        float p1 = __builtin_amdgcn_exp2f(sf[cf][1] - m_run);
        float p2 = __builtin_amdgcn_exp2f(sf[cf][2] - m_run);
        float p3 = __builtin_amdgcn_exp2f(sf[cf][3] - m_run);
        __hip_bfloat162 b01 = __float22bfloat162_rn(make_float2(p0, p1));
        __hip_bfloat162 b23 = __float22bfloat162_rn(make_float2(p2, p3));
        uint2 pkv;
        __builtin_memcpy(&pkv.x, &b01, 4);
        __builtin_memcpy(&pkv.y, &b23, 4);
        *(uint2*)&Pw[lm * 72 + cf * 16 + l4 * 4] = pkv;
    }

    // O^T += V^T P^T ; ones-row gives the running denominator
    #pragma unroll
    for (int ks = 0; ks < 2; ++ks) {
        bf16x8 pf = *(const bf16x8*)&Pw[lm * 72 + ks * 32 + l4 * 8];
        #pragma unroll
        for (int df = 0; df < 4; ++df) {
            const int rowV = df * 16 + lm;
            const int ch = l4 + 4 * ks;
            bf16x8 vf = *(const bf16x8*)(Vbuf + rowV * 64 + ((ch ^ (rowV & 7)) << 3));
            o[df] = MFMA16(vf, pf, o[df]);
        }
        ol = MFMA16(ones, pf, ol);
    }
}

__global__ __launch_bounds__(256) void attn_kernel(
    const ushort_t* __restrict__ Qg, const ushort_t* __restrict__ Kg,
    const ushort_t* __restrict__ Vtg, ushort_t* __restrict__ Og)
{
    __shared__ ushort_t Ks[2][64 * 64];
    __shared__ ushort_t Vs[2][64 * 64];
    __shared__ ushort_t Ps[4][16 * 72];
    const int t = threadIdx.x, l = t & 63, w = t >> 6;
    const int l4 = l >> 4, lm = l & 15;
    const int bh = blockIdx.x;
    const int qt = 31 - (int)blockIdx.y;        // heavy q-tiles first
    const int q0 = qt * 64, q0w = q0 + w * 16;
    const int qrow = q0w + lm;

    bf16x8 qf[2];
    {
        const ushort_t* qp = Qg + ((size_t)bh * 2048 + qrow) * 64 + l4 * 8;
        qf[0] = *(const bf16x8*)qp;
        qf[1] = *(const bf16x8*)(qp + 32);
    }
    bf16x8 ones;
    #pragma unroll
    for (int i = 0; i < 8; ++i) ones[i] = (short)0x3F80;

    f32x4 o[4] = {};
    f32x4 ol = {};
    float m_run = -1e30f;

    const int nkv = qt + 1, last = nkv - 1;
    const int srow = t >> 3, scol = t & 7;
    const ushort_t* kg0 = Kg + ((size_t)bh * 2048 + srow) * 64 + (scol ^ (srow & 7)) * 8;
    const ushort_t* vg0 = Vtg + ((size_t)bh * 64 + srow) * 2048 + (scol ^ (srow & 7)) * 8;

    // prologue: stage tile 0 -> buf 0
    async_copy16((char*)&Ks[0][0] + t * 16, kg0);
    async_copy16((char*)&Vs[0][0] + t * 16, vg0);
    async_copy16((char*)&Ks[0][0] + 4096 + t * 16, kg0 + 32 * 64);
    async_copy16((char*)&Vs[0][0] + 4096 + t * 16, vg0 + 32 * 2048);
    __syncthreads();

    for (int kt = 0; kt < last; ++kt) {
        const int cur = kt & 1;
        const size_t koff = (size_t)(kt + 1) * 64 * 64;   // next K tile offset
        const size_t voff = (size_t)(kt + 1) * 64;        // next V^T col offset
        async_copy16((char*)&Ks[cur ^ 1][0] + t * 16, kg0 + koff);
        async_copy16((char*)&Vs[cur ^ 1][0] + t * 16, vg0 + voff);
        async_copy16((char*)&Ks[cur ^ 1][0] + 4096 + t * 16, kg0 + koff + 32 * 64);
        async_copy16((char*)&Vs[cur ^ 1][0] + 4096 + t * 16, vg0 + voff + 32 * 2048);

        attn_tile<false>(&Ks[cur][0], &Vs[cur][0], &Ps[w][0],
                         qf, ones, o, ol, m_run, kt * 64, qrow, l4, lm);
        __syncthreads();
    }
    attn_tile<true>(&Ks[last & 1][0], &Vs[last & 1][0], &Ps[w][0],
                    qf, ones, o, ol, m_run, last * 64, qrow, l4, lm);

    const int b = bh >> 4, h = bh & 15;
    const float inv = 1.f / ol[0];
    #pragma unroll
    for (int df = 0; df < 4; ++df) {
        ushort4 pk4;
        pk4.x = f2bf(o[df][0] * inv); pk4.y = f2bf(o[df][1] * inv);
        pk4.z = f2bf(o[df][2] * inv); pk4.w = f2bf(o[df][3] * inv);
        *(ushort4*)&Og[((size_t)(b * 2048 + qrow)) * 1024 + h * 64 + df * 16 + l4 * 4] = pk4;
    }
}

// ---------------------------------------------------------------- launch
extern "C" void kernel_launch(void* const* d_in, const int* in_sizes, int n_in,
                              void* d_out, int out_size, void* d_ws, size_t ws_size,
                              hipStream_t stream)
{
    const float* x  = (const float*)d_in[0];
    const float* Wq = (const float*)d_in[1];
    const float* Wk = (const float*)d_in[2];
    const float* Wv = (const float*)d_in[3];
    const float* Wo = (const float*)d_in[4];

    ushort_t* ws  = (ushort_t*)d_ws;
    ushort_t* xb  = ws;
    ushort_t* wqb = ws + 4194304;          // Wq|Wk|Wv contiguous = [3072][1024]
    ushort_t* wob = ws + 7340032;
    ushort_t* Qw  = ws + 8388608;          // [bh][s][64] (pre-scaled)
    ushort_t* Kw  = ws + 12582912;         // [bh][s][64]
    ushort_t* Vtw = ws + 16777216;         // [bh][d][s]
    ushort_t* Aow = ws + 20971520;         // [b][s][1024]

    cvt_kernel<<<4096, 256, 0, stream>>>(x, Wq, Wk, Wv, Wo, ws);
    gemm_bt<<<dim3(24, 32), 256, 0, stream>>>(xb, wqb, Qw, Kw, Vtw, nullptr, 0);
    attn_kernel<<<dim3(32, 32), 256, 0, stream>>>(Qw, Kw, Vtw, Aow);
    gemm_bt<<<dim3(8, 32), 256, 0, stream>>>(Aow, wob, nullptr, nullptr, nullptr,
                                             (float*)d_out, 1);
}

// Round 7
// 117.560 us; speedup vs baseline: 1.8940x; 1.0226x over previous
//
#include <hip/hip_runtime.h>
#include <hip/hip_bf16.h>
#include <math.h>

typedef unsigned short ushort_t;
typedef __attribute__((ext_vector_type(8))) short bf16x8;
typedef __attribute__((ext_vector_type(4))) float f32x4;

#define MFMA16(a,b,c) __builtin_amdgcn_mfma_f32_16x16x32_bf16(a,b,c,0,0,0)
#define QSCALE 0.1803368801111204f   /* 0.125 * log2(e) : softmax in base-2 */

typedef unsigned int u32;
typedef __attribute__((address_space(1))) const u32* gp1_t;
typedef __attribute__((address_space(3))) u32* lp3_t;

__device__ __forceinline__ void async_copy16(void* l, const void* g) {
    __builtin_amdgcn_global_load_lds((gp1_t)g, (lp3_t)l, 16, 0, 0);
}

__device__ __forceinline__ ushort_t f2bf(float f) {
    unsigned u = __float_as_uint(f);
    unsigned r = u + 0x7fffu + ((u >> 16) & 1u);
    return (ushort_t)(r >> 16);
}

// ---------------------------------------------------------------- convert
__global__ __launch_bounds__(256) void cvt_kernel(
    const float* __restrict__ x,  const float* __restrict__ wq,
    const float* __restrict__ wk, const float* __restrict__ wv,
    const float* __restrict__ wo, ushort_t* __restrict__ dst)
{
    size_t base = ((size_t)blockIdx.x * 256 + threadIdx.x) * 8;
    const float* src; size_t off;
    if      (base < 4194304ul) { src = x;  off = base; }
    else if (base < 5242880ul) { src = wq; off = base - 4194304ul; }
    else if (base < 6291456ul) { src = wk; off = base - 5242880ul; }
    else if (base < 7340032ul) { src = wv; off = base - 6291456ul; }
    else                       { src = wo; off = base - 7340032ul; }
    float4 a = *(const float4*)(src + off);
    float4 b = *(const float4*)(src + off + 4);
    struct alignas(16) U8 { ushort_t v[8]; } o;
    o.v[0]=f2bf(a.x); o.v[1]=f2bf(a.y); o.v[2]=f2bf(a.z); o.v[3]=f2bf(a.w);
    o.v[4]=f2bf(b.x); o.v[5]=f2bf(b.y); o.v[6]=f2bf(b.z); o.v[7]=f2bf(b.w);
    *(U8*)(dst + base) = o;
}

// ---------------------------------------------------------------- GEMM
// C[m,n] = sum_k A[m,k]*B[n,k]; row-major, K contiguous. M=4096, K=1024.
// is_out=0: B = concat(Wq,Wk,Wv) [3072x1024], grid x=24; epilogue routed by n.
// is_out=1: B [1024x1024], grid x=8; C -> fp32 [m][n]
// Double-buffered LDS; counted vmcnt (loads stay in flight across barriers):
//   issue prefetch(kt+1) ; vmcnt(8) ; barrier ; compute(kt) ; lgkmcnt(0) ; barrier
__global__ __launch_bounds__(256) void gemm_bt(
    const ushort_t* __restrict__ A, const ushort_t* __restrict__ B,
    ushort_t* __restrict__ Oq, ushort_t* __restrict__ Ok,
    ushort_t* __restrict__ Ovt, float* __restrict__ Of, int is_out)
{
    __shared__ ushort_t As[2][128 * 64];
    __shared__ ushort_t Bs[2][128 * 64];
    const int t = threadIdx.x, l = t & 63, w = t >> 6;
    const int l4 = l >> 4, lm = l & 15;
    const int wr = w >> 1, wc = w & 1;

    // XCD-aware bijective swizzle (nwg % 8 == 0 for both grids)
    const int nwg = gridDim.x * gridDim.y;
    const int orig = (int)blockIdx.y * gridDim.x + (int)blockIdx.x;
    const int qq = nwg >> 3;
    const int swz = (orig & 7) * qq + (orig >> 3);
    const int n0 = (swz % gridDim.x) * 128;
    const int m0 = (swz / gridDim.x) * 128;

    const int srow = t >> 3, scol = t & 7;

    f32x4 acc[4][4] = {};

    // prologue: stage K-tile 0 -> buf 0 (8 loads in flight)
    #pragma unroll
    for (int i = 0; i < 4; ++i) {
        const int row = i * 32 + srow;
        const int c = scol ^ (row & 7);
        async_copy16((char*)&As[0][0] + i * 4096 + t * 16,
                     A + (size_t)(m0 + row) * 1024 + c * 8);
        async_copy16((char*)&Bs[0][0] + i * 4096 + t * 16,
                     B + (size_t)(n0 + row) * 1024 + c * 8);
    }

    for (int kt = 0; kt < 16; ++kt) {
        const int cur = kt & 1;
        if (kt + 1 < 16) {              // prefetch next tile; stays in flight
            const int k0 = (kt + 1) * 64;
            #pragma unroll
            for (int i = 0; i < 4; ++i) {
                const int row = i * 32 + srow;
                const int c = scol ^ (row & 7);
                async_copy16((char*)&As[cur ^ 1][0] + i * 4096 + t * 16,
                             A + (size_t)(m0 + row) * 1024 + k0 + c * 8);
                async_copy16((char*)&Bs[cur ^ 1][0] + i * 4096 + t * 16,
                             B + (size_t)(n0 + row) * 1024 + k0 + c * 8);
            }
            // own tile-kt loads retired (8 newest may stay outstanding)
            asm volatile("s_waitcnt vmcnt(8)" ::: "memory");
        } else {
            asm volatile("s_waitcnt vmcnt(0)" ::: "memory");
        }
        __builtin_amdgcn_s_barrier();   // ALL waves have tile kt in LDS

        #pragma unroll
        for (int ks = 0; ks < 2; ++ks) {
            bf16x8 af[4], bfr[4];
            #pragma unroll
            for (int mi = 0; mi < 4; ++mi) {
                const int row = wr * 64 + mi * 16 + lm;
                const int ch = l4 + 4 * ks;
                af[mi] = *(const bf16x8*)(&As[cur][0] + row * 64 + ((ch ^ (row & 7)) << 3));
            }
            #pragma unroll
            for (int ni = 0; ni < 4; ++ni) {
                const int row = wc * 64 + ni * 16 + lm;
                const int ch = l4 + 4 * ks;
                bfr[ni] = *(const bf16x8*)(&Bs[cur][0] + row * 64 + ((ch ^ (row & 7)) << 3));
            }
            #pragma unroll
            for (int mi = 0; mi < 4; ++mi)
                #pragma unroll
                for (int ni = 0; ni < 4; ++ni)
                    acc[mi][ni] = MFMA16(af[mi], bfr[ni], acc[mi][ni]);
        }
        asm volatile("s_waitcnt lgkmcnt(0)" ::: "memory");
        __builtin_amdgcn_s_barrier();   // all reads of buf[cur] done -> reusable
    }

    const int mb = m0 + wr * 64, nb = n0 + wc * 64;
    if (is_out) {
        #pragma unroll
        for (int mi = 0; mi < 4; ++mi)
            #pragma unroll
            for (int ni = 0; ni < 4; ++ni) {
                const int n = nb + ni * 16 + lm;
                const int mr = mb + mi * 16 + l4 * 4;
                #pragma unroll
                for (int r = 0; r < 4; ++r)
                    Of[(size_t)(mr + r) * 1024 + n] = acc[mi][ni][r];
            }
    } else if (nb >= 2048) {            // V^T region
        #pragma unroll
        for (int mi = 0; mi < 4; ++mi)
            #pragma unroll
            for (int ni = 0; ni < 4; ++ni) {
                const int nv = nb - 2048 + ni * 16 + lm;
                const int m = mb + mi * 16 + l4 * 4;
                const int b = m >> 11, s = m & 2047, h = nv >> 6, d = nv & 63;
                ushort4 pk;
                pk.x = f2bf(acc[mi][ni][0]); pk.y = f2bf(acc[mi][ni][1]);
                pk.z = f2bf(acc[mi][ni][2]); pk.w = f2bf(acc[mi][ni][3]);
                *(ushort4*)(Ovt + (((size_t)(b * 16 + h) * 64 + d) * 2048 + s)) = pk;
            }
    } else {                            // Q (scaled) or K region
        ushort_t* O = (nb < 1024) ? Oq : Ok;
        const float qs = (nb < 1024) ? (float)QSCALE : 1.0f;
        const int nbase = nb & 1023;
        #pragma unroll
        for (int mi = 0; mi < 4; ++mi)
            #pragma unroll
            for (int ni = 0; ni < 4; ++ni) {
                const int n = nbase + ni * 16 + lm;
                const int h = n >> 6, d = n & 63;
                #pragma unroll
                for (int r = 0; r < 4; ++r) {
                    const int m = mb + mi * 16 + l4 * 4 + r;
                    const int b = m >> 11, s = m & 2047;
                    O[((size_t)(b * 16 + h) * 2048 + s) * 64 + d] =
                        f2bf(acc[mi][ni][r] * qs);
                }
            }
    }
}

// ---------------------------------------------------------------- attention
// Q pre-scaled by 0.125*log2e -> softmax computed base-2.
// Swapped QK^T / PV; l tracked as a ones-row MFMA accumulator (rides defer-max).
template<bool MASK>
__device__ __forceinline__ void attn_tile(
    const ushort_t* Kbuf, const ushort_t* Vbuf, ushort_t* Pw,
    const bf16x8 (&qf)[2], const bf16x8 ones,
    f32x4 (&o)[4], f32x4& ol, float& m_run,
    int kv0, int qrow, int l4, int lm)
{
    // S^T = K Q^T : lane lm owns q-row, regs span k
    f32x4 sf[4] = {};
    #pragma unroll
    for (int ks = 0; ks < 2; ++ks)
        #pragma unroll
        for (int cf = 0; cf < 4; ++cf) {
            const int rowK = cf * 16 + lm;
            const int ch = l4 + 4 * ks;
            bf16x8 kf = *(const bf16x8*)(Kbuf + rowK * 64 + ((ch ^ (rowK & 7)) << 3));
            sf[cf] = MFMA16(kf, qf[ks], sf[cf]);
        }

    float tmax = -1e30f;
    #pragma unroll
    for (int cf = 0; cf < 4; ++cf)
        #pragma unroll
        for (int r = 0; r < 4; ++r) {
            float v = sf[cf][r];
            if (MASK && (kv0 + cf * 16 + l4 * 4 + r > qrow)) v = -30000.f;
            sf[cf][r] = v;
            tmax = fmaxf(tmax, v);
        }
    tmax = fmaxf(tmax, __shfl_xor(tmax, 16));
    tmax = fmaxf(tmax, __shfl_xor(tmax, 32));

    // defer-max (THR=8 in log2 units -> P bounded by 256)
    if (!__all(tmax <= m_run + 8.f)) {
        const float mn = fmaxf(m_run, tmax);
        const float alpha = __builtin_amdgcn_exp2f(m_run - mn);
        #pragma unroll
        for (int df = 0; df < 4; ++df)
            #pragma unroll
            for (int r = 0; r < 4; ++r)
                o[df][r] *= alpha;
        #pragma unroll
        for (int r = 0; r < 4; ++r) ol[r] *= alpha;
        m_run = mn;
    }

    // P = 2^(s - m), pack pairs (compiler emits v_cvt_pk_bf16_f32)
    #pragma unroll
    for (int cf = 0; cf < 4; ++cf) {
        float p0 = __builtin_amdgcn_exp2f(sf[cf][0] - m_run);
        float p1 = __builtin_amdgcn_exp2f(sf[cf][1] - m_run);
        float p2 = __builtin_amdgcn_exp2f(sf[cf][2] - m_run);
        float p3 = __builtin_amdgcn_exp2f(sf[cf][3] - m_run);
        __hip_bfloat162 b01 = __float22bfloat162_rn(make_float2(p0, p1));
        __hip_bfloat162 b23 = __float22bfloat162_rn(make_float2(p2, p3));
        uint2 pkv;
        __builtin_memcpy(&pkv.x, &b01, 4);
        __builtin_memcpy(&pkv.y, &b23, 4);
        *(uint2*)&Pw[lm * 72 + cf * 16 + l4 * 4] = pkv;
    }

    // O^T += V^T P^T ; ones-row gives the running denominator
    #pragma unroll
    for (int ks = 0; ks < 2; ++ks) {
        bf16x8 pf = *(const bf16x8*)&Pw[lm * 72 + ks * 32 + l4 * 8];
        #pragma unroll
        for (int df = 0; df < 4; ++df) {
            const int rowV = df * 16 + lm;
            const int ch = l4 + 4 * ks;
            bf16x8 vf = *(const bf16x8*)(Vbuf + rowV * 64 + ((ch ^ (rowV & 7)) << 3));
            o[df] = MFMA16(vf, pf, o[df]);
        }
        ol = MFMA16(ones, pf, ol);
    }
}

__global__ __launch_bounds__(256) void attn_kernel(
    const ushort_t* __restrict__ Qg, const ushort_t* __restrict__ Kg,
    const ushort_t* __restrict__ Vtg, ushort_t* __restrict__ Og)
{
    __shared__ ushort_t Ks[2][64 * 64];
    __shared__ ushort_t Vs[2][64 * 64];
    __shared__ ushort_t Ps[4][16 * 72];
    const int t = threadIdx.x, l = t & 63, w = t >> 6;
    const int l4 = l >> 4, lm = l & 15;
    const int bh = blockIdx.x;
    const int qt = 31 - (int)blockIdx.y;        // heavy q-tiles first
    const int q0 = qt * 64, q0w = q0 + w * 16;
    const int qrow = q0w + lm;

    bf16x8 qf[2];
    {
        const ushort_t* qp = Qg + ((size_t)bh * 2048 + qrow) * 64 + l4 * 8;
        qf[0] = *(const bf16x8*)qp;
        qf[1] = *(const bf16x8*)(qp + 32);
    }
    bf16x8 ones;
    #pragma unroll
    for (int i = 0; i < 8; ++i) ones[i] = (short)0x3F80;

    f32x4 o[4] = {};
    f32x4 ol = {};
    float m_run = -1e30f;

    const int nkv = qt + 1, last = nkv - 1;
    const int srow = t >> 3, scol = t & 7;
    const ushort_t* kg0 = Kg + ((size_t)bh * 2048 + srow) * 64 + (scol ^ (srow & 7)) * 8;
    const ushort_t* vg0 = Vtg + ((size_t)bh * 64 + srow) * 2048 + (scol ^ (srow & 7)) * 8;

    // prologue: stage tile 0 -> buf 0
    async_copy16((char*)&Ks[0][0] + t * 16, kg0);
    async_copy16((char*)&Vs[0][0] + t * 16, vg0);
    async_copy16((char*)&Ks[0][0] + 4096 + t * 16, kg0 + 32 * 64);
    async_copy16((char*)&Vs[0][0] + 4096 + t * 16, vg0 + 32 * 2048);
    __syncthreads();

    for (int kt = 0; kt < last; ++kt) {
        const int cur = kt & 1;
        const size_t koff = (size_t)(kt + 1) * 64 * 64;   // next K tile offset
        const size_t voff = (size_t)(kt + 1) * 64;        // next V^T col offset
        async_copy16((char*)&Ks[cur ^ 1][0] + t * 16, kg0 + koff);
        async_copy16((char*)&Vs[cur ^ 1][0] + t * 16, vg0 + voff);
        async_copy16((char*)&Ks[cur ^ 1][0] + 4096 + t * 16, kg0 + koff + 32 * 64);
        async_copy16((char*)&Vs[cur ^ 1][0] + 4096 + t * 16, vg0 + voff + 32 * 2048);

        attn_tile<false>(&Ks[cur][0], &Vs[cur][0], &Ps[w][0],
                         qf, ones, o, ol, m_run, kt * 64, qrow, l4, lm);
        __syncthreads();
    }
    attn_tile<true>(&Ks[last & 1][0], &Vs[last & 1][0], &Ps[w][0],
                    qf, ones, o, ol, m_run, last * 64, qrow, l4, lm);

    const int b = bh >> 4, h = bh & 15;
    const float inv = 1.f / ol[0];
    #pragma unroll
    for (int df = 0; df < 4; ++df) {
        ushort4 pk4;
        pk4.x = f2bf(o[df][0] * inv); pk4.y = f2bf(o[df][1] * inv);
        pk4.z = f2bf(o[df][2] * inv); pk4.w = f2bf(o[df][3] * inv);
        *(ushort4*)&Og[((size_t)(b * 2048 + qrow)) * 1024 + h * 64 + df * 16 + l4 * 4] = pk4;
    }
}

// ---------------------------------------------------------------- launch
extern "C" void kernel_launch(void* const* d_in, const int* in_sizes, int n_in,
                              void* d_out, int out_size, void* d_ws, size_t ws_size,
                              hipStream_t stream)
{
    const float* x  = (const float*)d_in[0];
    const float* Wq = (const float*)d_in[1];
    const float* Wk = (const float*)d_in[2];
    const float* Wv = (const float*)d_in[3];
    const float* Wo = (const float*)d_in[4];

    ushort_t* ws  = (ushort_t*)d_ws;
    ushort_t* xb  = ws;
    ushort_t* wqb = ws + 4194304;          // Wq|Wk|Wv contiguous = [3072][1024]
    ushort_t* wob = ws + 7340032;
    ushort_t* Qw  = ws + 8388608;          // [bh][s][64] (pre-scaled)
    ushort_t* Kw  = ws + 12582912;         // [bh][s][64]
    ushort_t* Vtw = ws + 16777216;         // [bh][d][s]
    ushort_t* Aow = ws + 20971520;         // [b][s][1024]

    cvt_kernel<<<4096, 256, 0, stream>>>(x, Wq, Wk, Wv, Wo, ws);
    gemm_bt<<<dim3(24, 32), 256, 0, stream>>>(xb, wqb, Qw, Kw, Vtw, nullptr, 0);
    attn_kernel<<<dim3(32, 32), 256, 0, stream>>>(Qw, Kw, Vtw, Aow);
    gemm_bt<<<dim3(8, 32), 256, 0, stream>>>(Aow, wob, nullptr, nullptr, nullptr,
                                             (float*)d_out, 1);
}

// Round 8
// 117.354 us; speedup vs baseline: 1.8973x; 1.0018x over previous
//
#include <hip/hip_runtime.h>
#include <hip/hip_bf16.h>
#include <math.h>

typedef unsigned short ushort_t;
typedef __attribute__((ext_vector_type(8))) short bf16x8;
typedef __attribute__((ext_vector_type(4))) float f32x4;

#define MFMA16(a,b,c) __builtin_amdgcn_mfma_f32_16x16x32_bf16(a,b,c,0,0,0)
#define QSCALE 0.1803368801111204f   /* 0.125 * log2(e) : softmax in base-2 */

typedef unsigned int u32;
typedef __attribute__((address_space(1))) const u32* gp1_t;
typedef __attribute__((address_space(3))) u32* lp3_t;

__device__ __forceinline__ void async_copy16(void* l, const void* g) {
    __builtin_amdgcn_global_load_lds((gp1_t)g, (lp3_t)l, 16, 0, 0);
}

__device__ __forceinline__ ushort_t f2bf(float f) {
    unsigned u = __float_as_uint(f);
    unsigned r = u + 0x7fffu + ((u >> 16) & 1u);
    return (ushort_t)(r >> 16);
}

// ---------------------------------------------------------------- convert
__global__ __launch_bounds__(256) void cvt_kernel(
    const float* __restrict__ x,  const float* __restrict__ wq,
    const float* __restrict__ wk, const float* __restrict__ wv,
    const float* __restrict__ wo, ushort_t* __restrict__ dst)
{
    size_t base = ((size_t)blockIdx.x * 256 + threadIdx.x) * 8;
    const float* src; size_t off;
    if      (base < 4194304ul) { src = x;  off = base; }
    else if (base < 5242880ul) { src = wq; off = base - 4194304ul; }
    else if (base < 6291456ul) { src = wk; off = base - 5242880ul; }
    else if (base < 7340032ul) { src = wv; off = base - 6291456ul; }
    else                       { src = wo; off = base - 7340032ul; }
    float4 a = *(const float4*)(src + off);
    float4 b = *(const float4*)(src + off + 4);
    struct alignas(16) U8 { ushort_t v[8]; } o;
    o.v[0]=f2bf(a.x); o.v[1]=f2bf(a.y); o.v[2]=f2bf(a.z); o.v[3]=f2bf(a.w);
    o.v[4]=f2bf(b.x); o.v[5]=f2bf(b.y); o.v[6]=f2bf(b.z); o.v[7]=f2bf(b.w);
    *(U8*)(dst + base) = o;
}

// ---------------------------------------------------------------- GEMM
// C[m,n] = sum_k A[m,k]*B[n,k]; row-major, K contiguous. M=4096, K=1024.
// 512 threads = 8 waves (4 wr x 2 wc), wave tile 32x64, 128^2 block tile.
// Double-buffered LDS; counted vmcnt: prefetch stays in flight across barrier.
// is_out=0: B = concat(Wq,Wk,Wv) [3072x1024]; epilogue routed by n.
// is_out=1: B [1024x1024]; C -> fp32 [m][n]
__global__ __launch_bounds__(512) void gemm_bt(
    const ushort_t* __restrict__ A, const ushort_t* __restrict__ B,
    ushort_t* __restrict__ Oq, ushort_t* __restrict__ Ok,
    ushort_t* __restrict__ Ovt, float* __restrict__ Of, int is_out)
{
    __shared__ ushort_t As[2][128 * 64];
    __shared__ ushort_t Bs[2][128 * 64];
    const int t = threadIdx.x, l = t & 63, w = t >> 6;
    const int l4 = l >> 4, lm = l & 15;
    const int wr = w >> 1, wc = w & 1;       // 4 x 2 waves

    // XCD-aware bijective swizzle (nwg % 8 == 0 for both grids)
    const int nwg = gridDim.x * gridDim.y;
    const int orig = (int)blockIdx.y * gridDim.x + (int)blockIdx.x;
    const int qq = nwg >> 3;
    const int swz = (orig & 7) * qq + (orig >> 3);
    const int n0 = (swz % gridDim.x) * 128;
    const int m0 = (swz / gridDim.x) * 128;

    const int srow = t >> 3, scol = t & 7;   // t < 512: srow 0..63

    f32x4 acc[2][4] = {};

    // prologue: stage K-tile 0 -> buf 0 (4 loads/thread in flight)
    #pragma unroll
    for (int i = 0; i < 2; ++i) {
        const int row = i * 64 + srow;
        const int c = scol ^ (row & 7);
        async_copy16((char*)&As[0][0] + i * 8192 + t * 16,
                     A + (size_t)(m0 + row) * 1024 + c * 8);
        async_copy16((char*)&Bs[0][0] + i * 8192 + t * 16,
                     B + (size_t)(n0 + row) * 1024 + c * 8);
    }

    for (int kt = 0; kt < 16; ++kt) {
        const int cur = kt & 1;
        if (kt + 1 < 16) {              // prefetch next tile; stays in flight
            const int k0 = (kt + 1) * 64;
            #pragma unroll
            for (int i = 0; i < 2; ++i) {
                const int row = i * 64 + srow;
                const int c = scol ^ (row & 7);
                async_copy16((char*)&As[cur ^ 1][0] + i * 8192 + t * 16,
                             A + (size_t)(m0 + row) * 1024 + k0 + c * 8);
                async_copy16((char*)&Bs[cur ^ 1][0] + i * 8192 + t * 16,
                             B + (size_t)(n0 + row) * 1024 + k0 + c * 8);
            }
            asm volatile("s_waitcnt vmcnt(4)" ::: "memory");
        } else {
            asm volatile("s_waitcnt vmcnt(0)" ::: "memory");
        }
        __builtin_amdgcn_s_barrier();   // ALL waves have tile kt in LDS

        #pragma unroll
        for (int ks = 0; ks < 2; ++ks) {
            bf16x8 af[2], bfr[4];
            #pragma unroll
            for (int mi = 0; mi < 2; ++mi) {
                const int row = wr * 32 + mi * 16 + lm;
                const int ch = l4 + 4 * ks;
                af[mi] = *(const bf16x8*)(&As[cur][0] + row * 64 + ((ch ^ (row & 7)) << 3));
            }
            #pragma unroll
            for (int ni = 0; ni < 4; ++ni) {
                const int row = wc * 64 + ni * 16 + lm;
                const int ch = l4 + 4 * ks;
                bfr[ni] = *(const bf16x8*)(&Bs[cur][0] + row * 64 + ((ch ^ (row & 7)) << 3));
            }
            #pragma unroll
            for (int mi = 0; mi < 2; ++mi)
                #pragma unroll
                for (int ni = 0; ni < 4; ++ni)
                    acc[mi][ni] = MFMA16(af[mi], bfr[ni], acc[mi][ni]);
        }
        asm volatile("s_waitcnt lgkmcnt(0)" ::: "memory");
        __builtin_amdgcn_s_barrier();   // all reads of buf[cur] done -> reusable
    }

    const int mb = m0 + wr * 32, nb = n0 + wc * 64;
    if (is_out) {
        #pragma unroll
        for (int mi = 0; mi < 2; ++mi)
            #pragma unroll
            for (int ni = 0; ni < 4; ++ni) {
                const int n = nb + ni * 16 + lm;
                const int mr = mb + mi * 16 + l4 * 4;
                #pragma unroll
                for (int r = 0; r < 4; ++r)
                    Of[(size_t)(mr + r) * 1024 + n] = acc[mi][ni][r];
            }
    } else if (nb >= 2048) {            // V^T region
        #pragma unroll
        for (int mi = 0; mi < 2; ++mi)
            #pragma unroll
            for (int ni = 0; ni < 4; ++ni) {
                const int nv = nb - 2048 + ni * 16 + lm;
                const int m = mb + mi * 16 + l4 * 4;
                const int b = m >> 11, s = m & 2047, h = nv >> 6, d = nv & 63;
                ushort4 pk;
                pk.x = f2bf(acc[mi][ni][0]); pk.y = f2bf(acc[mi][ni][1]);
                pk.z = f2bf(acc[mi][ni][2]); pk.w = f2bf(acc[mi][ni][3]);
                *(ushort4*)(Ovt + (((size_t)(b * 16 + h) * 64 + d) * 2048 + s)) = pk;
            }
    } else {                            // Q (scaled) or K region
        ushort_t* O = (nb < 1024) ? Oq : Ok;
        const float qs = (nb < 1024) ? (float)QSCALE : 1.0f;
        const int nbase = nb & 1023;
        #pragma unroll
        for (int mi = 0; mi < 2; ++mi)
            #pragma unroll
            for (int ni = 0; ni < 4; ++ni) {
                const int n = nbase + ni * 16 + lm;
                const int h = n >> 6, d = n & 63;
                #pragma unroll
                for (int r = 0; r < 4; ++r) {
                    const int m = mb + mi * 16 + l4 * 4 + r;
                    const int b = m >> 11, s = m & 2047;
                    O[((size_t)(b * 16 + h) * 2048 + s) * 64 + d] =
                        f2bf(acc[mi][ni][r] * qs);
                }
            }
    }
}

// ---------------------------------------------------------------- attention
// 4 waves x 32 q-rows (2 fragments/wave) -> K/V LDS reads + staging per q halve.
// Q pre-scaled by 0.125*log2e -> softmax base-2. Swapped QK^T / PV.
// l tracked as ones-row MFMA accumulator (rides defer-max).
template<bool MASK>
__device__ __forceinline__ void attn_tile(
    const ushort_t* Kbuf, const ushort_t* Vbuf, ushort_t* Pw,
    const bf16x8 (&qf)[2][2], const bf16x8 ones,
    f32x4 (&o)[2][4], f32x4 (&ol)[2], float (&m_run)[2],
    int kv0, int q0w, int l4, int lm)
{
    // S^T = K Q^T for both q-fragments (K frag read once, used twice)
    f32x4 sf[2][4] = {};
    #pragma unroll
    for (int ks = 0; ks < 2; ++ks)
        #pragma unroll
        for (int cf = 0; cf < 4; ++cf) {
            const int rowK = cf * 16 + lm;
            const int ch = l4 + 4 * ks;
            bf16x8 kf = *(const bf16x8*)(Kbuf + rowK * 64 + ((ch ^ (rowK & 7)) << 3));
            sf[0][cf] = MFMA16(kf, qf[0][ks], sf[0][cf]);
            sf[1][cf] = MFMA16(kf, qf[1][ks], sf[1][cf]);
        }

    float tmax[2] = {-1e30f, -1e30f};
    #pragma unroll
    for (int qi = 0; qi < 2; ++qi) {
        const int qrow = q0w + qi * 16 + lm;
        #pragma unroll
        for (int cf = 0; cf < 4; ++cf)
            #pragma unroll
            for (int r = 0; r < 4; ++r) {
                float v = sf[qi][cf][r];
                if (MASK && (kv0 + cf * 16 + l4 * 4 + r > qrow)) v = -30000.f;
                sf[qi][cf][r] = v;
                tmax[qi] = fmaxf(tmax[qi], v);
            }
        tmax[qi] = fmaxf(tmax[qi], __shfl_xor(tmax[qi], 16));
        tmax[qi] = fmaxf(tmax[qi], __shfl_xor(tmax[qi], 32));
    }

    // defer-max (THR=8 in log2 units)
    if (!__all(fmaxf(tmax[0] - m_run[0], tmax[1] - m_run[1]) <= 8.f)) {
        #pragma unroll
        for (int qi = 0; qi < 2; ++qi) {
            const float mn = fmaxf(m_run[qi], tmax[qi]);
            const float alpha = __builtin_amdgcn_exp2f(m_run[qi] - mn);
            #pragma unroll
            for (int df = 0; df < 4; ++df)
                #pragma unroll
                for (int r = 0; r < 4; ++r)
                    o[qi][df][r] *= alpha;
            #pragma unroll
            for (int r = 0; r < 4; ++r) ol[qi][r] *= alpha;
            m_run[qi] = mn;
        }
    }

    // P = 2^(s - m), pack pairs -> wave-private LDS [32 q][72]
    #pragma unroll
    for (int qi = 0; qi < 2; ++qi)
        #pragma unroll
        for (int cf = 0; cf < 4; ++cf) {
            float p0 = __builtin_amdgcn_exp2f(sf[qi][cf][0] - m_run[qi]);
            float p1 = __builtin_amdgcn_exp2f(sf[qi][cf][1] - m_run[qi]);
            float p2 = __builtin_amdgcn_exp2f(sf[qi][cf][2] - m_run[qi]);
            float p3 = __builtin_amdgcn_exp2f(sf[qi][cf][3] - m_run[qi]);
            __hip_bfloat162 b01 = __float22bfloat162_rn(make_float2(p0, p1));
            __hip_bfloat162 b23 = __float22bfloat162_rn(make_float2(p2, p3));
            uint2 pkv;
            __builtin_memcpy(&pkv.x, &b01, 4);
            __builtin_memcpy(&pkv.y, &b23, 4);
            *(uint2*)&Pw[(qi * 16 + lm) * 72 + cf * 16 + l4 * 4] = pkv;
        }

    // O^T += V^T P^T ; V frag read once, used for both q-fragments
    #pragma unroll
    for (int ks = 0; ks < 2; ++ks) {
        bf16x8 pf0 = *(const bf16x8*)&Pw[(0 * 16 + lm) * 72 + ks * 32 + l4 * 8];
        bf16x8 pf1 = *(const bf16x8*)&Pw[(1 * 16 + lm) * 72 + ks * 32 + l4 * 8];
        #pragma unroll
        for (int df = 0; df < 4; ++df) {
            const int rowV = df * 16 + lm;
            const int ch = l4 + 4 * ks;
            bf16x8 vf = *(const bf16x8*)(Vbuf + rowV * 64 + ((ch ^ (rowV & 7)) << 3));
            o[0][df] = MFMA16(vf, pf0, o[0][df]);
            o[1][df] = MFMA16(vf, pf1, o[1][df]);
        }
        ol[0] = MFMA16(ones, pf0, ol[0]);
        ol[1] = MFMA16(ones, pf1, ol[1]);
    }
}

__global__ __launch_bounds__(256) void attn_kernel(
    const ushort_t* __restrict__ Qg, const ushort_t* __restrict__ Kg,
    const ushort_t* __restrict__ Vtg, ushort_t* __restrict__ Og)
{
    __shared__ ushort_t Ks[2][64 * 64];
    __shared__ ushort_t Vs[2][64 * 64];
    __shared__ ushort_t Ps[4][32 * 72];
    const int t = threadIdx.x, l = t & 63, w = t >> 6;
    const int l4 = l >> 4, lm = l & 15;
    const int bh = blockIdx.x;
    const int qt = 15 - (int)blockIdx.y;        // heavy q-tiles first
    const int q0 = qt * 128, q0w = q0 + w * 32;

    bf16x8 qf[2][2];
    #pragma unroll
    for (int qi = 0; qi < 2; ++qi) {
        const ushort_t* qp = Qg + ((size_t)bh * 2048 + q0w + qi * 16 + lm) * 64 + l4 * 8;
        qf[qi][0] = *(const bf16x8*)qp;
        qf[qi][1] = *(const bf16x8*)(qp + 32);
    }
    bf16x8 ones;
    #pragma unroll
    for (int i = 0; i < 8; ++i) ones[i] = (short)0x3F80;

    f32x4 o[2][4] = {};
    f32x4 ol[2] = {};
    float m_run[2] = {-1e30f, -1e30f};

    const int nkv = 2 * qt + 2;
    const int srow = t >> 3, scol = t & 7;
    const ushort_t* kg0 = Kg + ((size_t)bh * 2048 + srow) * 64 + (scol ^ (srow & 7)) * 8;
    const ushort_t* vg0 = Vtg + ((size_t)bh * 64 + srow) * 2048 + (scol ^ (srow & 7)) * 8;

    // prologue: stage tile 0 -> buf 0
    async_copy16((char*)&Ks[0][0] + t * 16, kg0);
    async_copy16((char*)&Vs[0][0] + t * 16, vg0);
    async_copy16((char*)&Ks[0][0] + 4096 + t * 16, kg0 + 32 * 64);
    async_copy16((char*)&Vs[0][0] + 4096 + t * 16, vg0 + 32 * 2048);
    __syncthreads();

    int kt = 0;
    for (; kt < nkv - 2; ++kt) {            // strictly-below-diagonal tiles
        const int cur = kt & 1;
        const size_t koff = (size_t)(kt + 1) * 64 * 64;
        const size_t voff = (size_t)(kt + 1) * 64;
        async_copy16((char*)&Ks[cur ^ 1][0] + t * 16, kg0 + koff);
        async_copy16((char*)&Vs[cur ^ 1][0] + t * 16, vg0 + voff);
        async_copy16((char*)&Ks[cur ^ 1][0] + 4096 + t * 16, kg0 + koff + 32 * 64);
        async_copy16((char*)&Vs[cur ^ 1][0] + 4096 + t * 16, vg0 + voff + 32 * 2048);

        attn_tile<false>(&Ks[cur][0], &Vs[cur][0], &Ps[w][0],
                         qf, ones, o, ol, m_run, kt * 64, q0w, l4, lm);
        __syncthreads();
    }
    for (; kt < nkv; ++kt) {                // diagonal-region tiles (masked)
        const int cur = kt & 1;
        if (kt + 1 < nkv) {
            const size_t koff = (size_t)(kt + 1) * 64 * 64;
            const size_t voff = (size_t)(kt + 1) * 64;
            async_copy16((char*)&Ks[cur ^ 1][0] + t * 16, kg0 + koff);
            async_copy16((char*)&Vs[cur ^ 1][0] + t * 16, vg0 + voff);
            async_copy16((char*)&Ks[cur ^ 1][0] + 4096 + t * 16, kg0 + koff + 32 * 64);
            async_copy16((char*)&Vs[cur ^ 1][0] + 4096 + t * 16, vg0 + voff + 32 * 2048);
        }
        attn_tile<true>(&Ks[cur][0], &Vs[cur][0], &Ps[w][0],
                        qf, ones, o, ol, m_run, kt * 64, q0w, l4, lm);
        __syncthreads();
    }

    const int b = bh >> 4, h = bh & 15;
    #pragma unroll
    for (int qi = 0; qi < 2; ++qi) {
        const float inv = 1.f / ol[qi][0];
        const int srow_o = q0w + qi * 16 + lm;
        #pragma unroll
        for (int df = 0; df < 4; ++df) {
            ushort4 pk4;
            pk4.x = f2bf(o[qi][df][0] * inv); pk4.y = f2bf(o[qi][df][1] * inv);
            pk4.z = f2bf(o[qi][df][2] * inv); pk4.w = f2bf(o[qi][df][3] * inv);
            *(ushort4*)&Og[((size_t)(b * 2048 + srow_o)) * 1024 + h * 64 + df * 16 + l4 * 4] = pk4;
        }
    }
}

// ---------------------------------------------------------------- launch
extern "C" void kernel_launch(void* const* d_in, const int* in_sizes, int n_in,
                              void* d_out, int out_size, void* d_ws, size_t ws_size,
                              hipStream_t stream)
{
    const float* x  = (const float*)d_in[0];
    const float* Wq = (const float*)d_in[1];
    const float* Wk = (const float*)d_in[2];
    const float* Wv = (const float*)d_in[3];
    const float* Wo = (const float*)d_in[4];

    ushort_t* ws  = (ushort_t*)d_ws;
    ushort_t* xb  = ws;
    ushort_t* wqb = ws + 4194304;          // Wq|Wk|Wv contiguous = [3072][1024]
    ushort_t* wob = ws + 7340032;
    ushort_t* Qw  = ws + 8388608;          // [bh][s][64] (pre-scaled)
    ushort_t* Kw  = ws + 12582912;         // [bh][s][64]
    ushort_t* Vtw = ws + 16777216;         // [bh][d][s]
    ushort_t* Aow = ws + 20971520;         // [b][s][1024]

    cvt_kernel<<<4096, 256, 0, stream>>>(x, Wq, Wk, Wv, Wo, ws);
    gemm_bt<<<dim3(24, 32), 512, 0, stream>>>(xb, wqb, Qw, Kw, Vtw, nullptr, 0);
    attn_kernel<<<dim3(32, 16), 256, 0, stream>>>(Qw, Kw, Vtw, Aow);
    gemm_bt<<<dim3(8, 32), 512, 0, stream>>>(Aow, wob, nullptr, nullptr, nullptr,
                                             (float*)d_out, 1);
}

// Round 9
// 107.595 us; speedup vs baseline: 2.0694x; 1.0907x over previous
//
#include <hip/hip_runtime.h>
#include <hip/hip_bf16.h>
#include <math.h>

typedef unsigned short ushort_t;
typedef __attribute__((ext_vector_type(8))) short bf16x8;
typedef __attribute__((ext_vector_type(4))) float f32x4;

#define MFMA16(a,b,c) __builtin_amdgcn_mfma_f32_16x16x32_bf16(a,b,c,0,0,0)
#define QSCALE 0.1803368801111204f   /* 0.125 * log2(e) : softmax in base-2 */

typedef unsigned int u32;
typedef __attribute__((address_space(1))) const u32* gp1_t;
typedef __attribute__((address_space(3))) u32* lp3_t;

__device__ __forceinline__ void async_copy16(void* l, const void* g) {
    __builtin_amdgcn_global_load_lds((gp1_t)g, (lp3_t)l, 16, 0, 0);
}

__device__ __forceinline__ ushort_t f2bf(float f) {
    unsigned u = __float_as_uint(f);
    unsigned r = u + 0x7fffu + ((u >> 16) & 1u);
    return (ushort_t)(r >> 16);
}

// ---------------------------------------------------------------- convert
__global__ __launch_bounds__(256) void cvt_kernel(
    const float* __restrict__ x,  const float* __restrict__ wq,
    const float* __restrict__ wk, const float* __restrict__ wv,
    const float* __restrict__ wo, ushort_t* __restrict__ dst)
{
    size_t base = ((size_t)blockIdx.x * 256 + threadIdx.x) * 8;
    const float* src; size_t off;
    if      (base < 4194304ul) { src = x;  off = base; }
    else if (base < 5242880ul) { src = wq; off = base - 4194304ul; }
    else if (base < 6291456ul) { src = wk; off = base - 5242880ul; }
    else if (base < 7340032ul) { src = wv; off = base - 6291456ul; }
    else                       { src = wo; off = base - 7340032ul; }
    float4 a = *(const float4*)(src + off);
    float4 b = *(const float4*)(src + off + 4);
    struct alignas(16) U8 { ushort_t v[8]; } o;
    o.v[0]=f2bf(a.x); o.v[1]=f2bf(a.y); o.v[2]=f2bf(a.z); o.v[3]=f2bf(a.w);
    o.v[4]=f2bf(b.x); o.v[5]=f2bf(b.y); o.v[6]=f2bf(b.z); o.v[7]=f2bf(b.w);
    *(U8*)(dst + base) = o;
}

// ---------------------------------------------------------------- GEMM
// C[m,n] = sum_k A[m,k]*B[n,k]; row-major, K contiguous. M=4096, K=1024.
// 512 threads = 8 waves (4 wr x 2 wc), wave tile 32x64, 128^2 block tile.
// Double-buffered LDS; counted vmcnt: prefetch stays in flight across barrier.
__global__ __launch_bounds__(512) void gemm_bt(
    const ushort_t* __restrict__ A, const ushort_t* __restrict__ B,
    ushort_t* __restrict__ Oq, ushort_t* __restrict__ Ok,
    ushort_t* __restrict__ Ovt, float* __restrict__ Of, int is_out)
{
    __shared__ ushort_t As[2][128 * 64];
    __shared__ ushort_t Bs[2][128 * 64];
    const int t = threadIdx.x, l = t & 63, w = t >> 6;
    const int l4 = l >> 4, lm = l & 15;
    const int wr = w >> 1, wc = w & 1;       // 4 x 2 waves

    // XCD-aware bijective swizzle (nwg % 8 == 0 for both grids)
    const int nwg = gridDim.x * gridDim.y;
    const int orig = (int)blockIdx.y * gridDim.x + (int)blockIdx.x;
    const int qq = nwg >> 3;
    const int swz = (orig & 7) * qq + (orig >> 3);
    const int n0 = (swz % gridDim.x) * 128;
    const int m0 = (swz / gridDim.x) * 128;

    const int srow = t >> 3, scol = t & 7;   // t < 512: srow 0..63

    f32x4 acc[2][4] = {};

    // prologue: stage K-tile 0 -> buf 0 (4 loads/thread in flight)
    #pragma unroll
    for (int i = 0; i < 2; ++i) {
        const int row = i * 64 + srow;
        const int c = scol ^ (row & 7);
        async_copy16((char*)&As[0][0] + i * 8192 + t * 16,
                     A + (size_t)(m0 + row) * 1024 + c * 8);
        async_copy16((char*)&Bs[0][0] + i * 8192 + t * 16,
                     B + (size_t)(n0 + row) * 1024 + c * 8);
    }

    for (int kt = 0; kt < 16; ++kt) {
        const int cur = kt & 1;
        if (kt + 1 < 16) {              // prefetch next tile; stays in flight
            const int k0 = (kt + 1) * 64;
            #pragma unroll
            for (int i = 0; i < 2; ++i) {
                const int row = i * 64 + srow;
                const int c = scol ^ (row & 7);
                async_copy16((char*)&As[cur ^ 1][0] + i * 8192 + t * 16,
                             A + (size_t)(m0 + row) * 1024 + k0 + c * 8);
                async_copy16((char*)&Bs[cur ^ 1][0] + i * 8192 + t * 16,
                             B + (size_t)(n0 + row) * 1024 + k0 + c * 8);
            }
            asm volatile("s_waitcnt vmcnt(4)" ::: "memory");
        } else {
            asm volatile("s_waitcnt vmcnt(0)" ::: "memory");
        }
        __builtin_amdgcn_s_barrier();   // ALL waves have tile kt in LDS

        #pragma unroll
        for (int ks = 0; ks < 2; ++ks) {
            bf16x8 af[2], bfr[4];
            #pragma unroll
            for (int mi = 0; mi < 2; ++mi) {
                const int row = wr * 32 + mi * 16 + lm;
                const int ch = l4 + 4 * ks;
                af[mi] = *(const bf16x8*)(&As[cur][0] + row * 64 + ((ch ^ (row & 7)) << 3));
            }
            #pragma unroll
            for (int ni = 0; ni < 4; ++ni) {
                const int row = wc * 64 + ni * 16 + lm;
                const int ch = l4 + 4 * ks;
                bfr[ni] = *(const bf16x8*)(&Bs[cur][0] + row * 64 + ((ch ^ (row & 7)) << 3));
            }
            #pragma unroll
            for (int mi = 0; mi < 2; ++mi)
                #pragma unroll
                for (int ni = 0; ni < 4; ++ni)
                    acc[mi][ni] = MFMA16(af[mi], bfr[ni], acc[mi][ni]);
        }
        asm volatile("s_waitcnt lgkmcnt(0)" ::: "memory");
        __builtin_amdgcn_s_barrier();   // all reads of buf[cur] done -> reusable
    }

    const int mb = m0 + wr * 32, nb = n0 + wc * 64;
    if (is_out) {
        #pragma unroll
        for (int mi = 0; mi < 2; ++mi)
            #pragma unroll
            for (int ni = 0; ni < 4; ++ni) {
                const int n = nb + ni * 16 + lm;
                const int mr = mb + mi * 16 + l4 * 4;
                #pragma unroll
                for (int r = 0; r < 4; ++r)
                    Of[(size_t)(mr + r) * 1024 + n] = acc[mi][ni][r];
            }
    } else if (nb >= 2048) {            // V^T region
        #pragma unroll
        for (int mi = 0; mi < 2; ++mi)
            #pragma unroll
            for (int ni = 0; ni < 4; ++ni) {
                const int nv = nb - 2048 + ni * 16 + lm;
                const int m = mb + mi * 16 + l4 * 4;
                const int b = m >> 11, s = m & 2047, h = nv >> 6, d = nv & 63;
                ushort4 pk;
                pk.x = f2bf(acc[mi][ni][0]); pk.y = f2bf(acc[mi][ni][1]);
                pk.z = f2bf(acc[mi][ni][2]); pk.w = f2bf(acc[mi][ni][3]);
                *(ushort4*)(Ovt + (((size_t)(b * 16 + h) * 64 + d) * 2048 + s)) = pk;
            }
    } else {                            // Q (scaled) or K region
        ushort_t* O = (nb < 1024) ? Oq : Ok;
        const float qs = (nb < 1024) ? (float)QSCALE : 1.0f;
        const int nbase = nb & 1023;
        #pragma unroll
        for (int mi = 0; mi < 2; ++mi)
            #pragma unroll
            for (int ni = 0; ni < 4; ++ni) {
                const int n = nbase + ni * 16 + lm;
                const int h = n >> 6, d = n & 63;
                #pragma unroll
                for (int r = 0; r < 4; ++r) {
                    const int m = mb + mi * 16 + l4 * 4 + r;
                    const int b = m >> 11, s = m & 2047;
                    O[((size_t)(b * 16 + h) * 2048 + s) * 64 + d] =
                        f2bf(acc[mi][ni][r] * qs);
                }
            }
    }
}

// ---------------------------------------------------------------- attention
// 8 waves x 16 q-rows (QBLK=128), KVBLK=64. 512 threads -> 1 K + 1 V load each.
// Q pre-scaled by 0.125*log2e -> softmax base-2. Swapped QK^T / PV.
// l tracked as ones-row MFMA accumulator (rides defer-max).
template<bool MASK>
__device__ __forceinline__ void attn_tile(
    const ushort_t* Kbuf, const ushort_t* Vbuf, ushort_t* Pw,
    const bf16x8 (&qf)[2], const bf16x8 ones,
    f32x4 (&o)[4], f32x4& ol, float& m_run,
    int kv0, int qrow, int l4, int lm)
{
    // S^T = K Q^T : lane lm owns q-row, regs span k
    f32x4 sf[4] = {};
    #pragma unroll
    for (int ks = 0; ks < 2; ++ks)
        #pragma unroll
        for (int cf = 0; cf < 4; ++cf) {
            const int rowK = cf * 16 + lm;
            const int ch = l4 + 4 * ks;
            bf16x8 kf = *(const bf16x8*)(Kbuf + rowK * 64 + ((ch ^ (rowK & 7)) << 3));
            sf[cf] = MFMA16(kf, qf[ks], sf[cf]);
        }

    float tmax = -1e30f;
    #pragma unroll
    for (int cf = 0; cf < 4; ++cf)
        #pragma unroll
        for (int r = 0; r < 4; ++r) {
            float v = sf[cf][r];
            if (MASK && (kv0 + cf * 16 + l4 * 4 + r > qrow)) v = -30000.f;
            sf[cf][r] = v;
            tmax = fmaxf(tmax, v);
        }
    tmax = fmaxf(tmax, __shfl_xor(tmax, 16));
    tmax = fmaxf(tmax, __shfl_xor(tmax, 32));

    // defer-max (THR=8 in log2 units -> P bounded by 256)
    if (!__all(tmax <= m_run + 8.f)) {
        const float mn = fmaxf(m_run, tmax);
        const float alpha = __builtin_amdgcn_exp2f(m_run - mn);
        #pragma unroll
        for (int df = 0; df < 4; ++df)
            #pragma unroll
            for (int r = 0; r < 4; ++r)
                o[df][r] *= alpha;
        #pragma unroll
        for (int r = 0; r < 4; ++r) ol[r] *= alpha;
        m_run = mn;
    }

    // P = 2^(s - m), pack pairs (compiler emits v_cvt_pk_bf16_f32)
    #pragma unroll
    for (int cf = 0; cf < 4; ++cf) {
        float p0 = __builtin_amdgcn_exp2f(sf[cf][0] - m_run);
        float p1 = __builtin_amdgcn_exp2f(sf[cf][1] - m_run);
        float p2 = __builtin_amdgcn_exp2f(sf[cf][2] - m_run);
        float p3 = __builtin_amdgcn_exp2f(sf[cf][3] - m_run);
        __hip_bfloat162 b01 = __float22bfloat162_rn(make_float2(p0, p1));
        __hip_bfloat162 b23 = __float22bfloat162_rn(make_float2(p2, p3));
        uint2 pkv;
        __builtin_memcpy(&pkv.x, &b01, 4);
        __builtin_memcpy(&pkv.y, &b23, 4);
        *(uint2*)&Pw[lm * 72 + cf * 16 + l4 * 4] = pkv;
    }

    // O^T += V^T P^T ; ones-row gives the running denominator
    #pragma unroll
    for (int ks = 0; ks < 2; ++ks) {
        bf16x8 pf = *(const bf16x8*)&Pw[lm * 72 + ks * 32 + l4 * 8];
        #pragma unroll
        for (int df = 0; df < 4; ++df) {
            const int rowV = df * 16 + lm;
            const int ch = l4 + 4 * ks;
            bf16x8 vf = *(const bf16x8*)(Vbuf + rowV * 64 + ((ch ^ (rowV & 7)) << 3));
            o[df] = MFMA16(vf, pf, o[df]);
        }
        ol = MFMA16(ones, pf, ol);
    }
}

__global__ __launch_bounds__(512) void attn_kernel(
    const ushort_t* __restrict__ Qg, const ushort_t* __restrict__ Kg,
    const ushort_t* __restrict__ Vtg, ushort_t* __restrict__ Og)
{
    __shared__ ushort_t Ks[2][64 * 64];
    __shared__ ushort_t Vs[2][64 * 64];
    __shared__ ushort_t Ps[8][16 * 72];
    const int t = threadIdx.x, l = t & 63, w = t >> 6;     // 8 waves
    const int l4 = l >> 4, lm = l & 15;
    const int bh = blockIdx.x;
    const int qt = 15 - (int)blockIdx.y;        // heavy q-tiles first
    const int q0 = qt * 128, q0w = q0 + w * 16;
    const int qrow = q0w + lm;

    bf16x8 qf[2];
    {
        const ushort_t* qp = Qg + ((size_t)bh * 2048 + qrow) * 64 + l4 * 8;
        qf[0] = *(const bf16x8*)qp;
        qf[1] = *(const bf16x8*)(qp + 32);
    }
    bf16x8 ones;
    #pragma unroll
    for (int i = 0; i < 8; ++i) ones[i] = (short)0x3F80;

    f32x4 o[4] = {};
    f32x4 ol = {};
    float m_run = -1e30f;

    const int nkv = 2 * qt + 2;
    const int srow = t >> 3, scol = t & 7;      // srow 0..63: full tile, 1 load each
    const ushort_t* kg0 = Kg + ((size_t)bh * 2048 + srow) * 64 + (scol ^ (srow & 7)) * 8;
    const ushort_t* vg0 = Vtg + ((size_t)bh * 64 + srow) * 2048 + (scol ^ (srow & 7)) * 8;

    // prologue: stage tile 0 -> buf 0
    async_copy16((char*)&Ks[0][0] + t * 16, kg0);
    async_copy16((char*)&Vs[0][0] + t * 16, vg0);
    __syncthreads();

    int kt = 0;
    for (; kt < nkv - 2; ++kt) {            // strictly-below-diagonal tiles
        const int cur = kt & 1;
        async_copy16((char*)&Ks[cur ^ 1][0] + t * 16, kg0 + (size_t)(kt + 1) * 4096);
        async_copy16((char*)&Vs[cur ^ 1][0] + t * 16, vg0 + (size_t)(kt + 1) * 64);

        attn_tile<false>(&Ks[cur][0], &Vs[cur][0], &Ps[w][0],
                         qf, ones, o, ol, m_run, kt * 64, qrow, l4, lm);
        __syncthreads();
    }
    for (; kt < nkv; ++kt) {                // diagonal-region tiles (masked)
        const int cur = kt & 1;
        if (kt + 1 < nkv) {
            async_copy16((char*)&Ks[cur ^ 1][0] + t * 16, kg0 + (size_t)(kt + 1) * 4096);
            async_copy16((char*)&Vs[cur ^ 1][0] + t * 16, vg0 + (size_t)(kt + 1) * 64);
        }
        attn_tile<true>(&Ks[cur][0], &Vs[cur][0], &Ps[w][0],
                        qf, ones, o, ol, m_run, kt * 64, qrow, l4, lm);
        __syncthreads();
    }

    const int b = bh >> 4, h = bh & 15;
    const float inv = 1.f / ol[0];
    #pragma unroll
    for (int df = 0; df < 4; ++df) {
        ushort4 pk4;
        pk4.x = f2bf(o[df][0] * inv); pk4.y = f2bf(o[df][1] * inv);
        pk4.z = f2bf(o[df][2] * inv); pk4.w = f2bf(o[df][3] * inv);
        *(ushort4*)&Og[((size_t)(b * 2048 + qrow)) * 1024 + h * 64 + df * 16 + l4 * 4] = pk4;
    }
}

// ---------------------------------------------------------------- launch
extern "C" void kernel_launch(void* const* d_in, const int* in_sizes, int n_in,
                              void* d_out, int out_size, void* d_ws, size_t ws_size,
                              hipStream_t stream)
{
    const float* x  = (const float*)d_in[0];
    const float* Wq = (const float*)d_in[1];
    const float* Wk = (const float*)d_in[2];
    const float* Wv = (const float*)d_in[3];
    const float* Wo = (const float*)d_in[4];

    ushort_t* ws  = (ushort_t*)d_ws;
    ushort_t* xb  = ws;
    ushort_t* wqb = ws + 4194304;          // Wq|Wk|Wv contiguous = [3072][1024]
    ushort_t* wob = ws + 7340032;
    ushort_t* Qw  = ws + 8388608;          // [bh][s][64] (pre-scaled)
    ushort_t* Kw  = ws + 12582912;         // [bh][s][64]
    ushort_t* Vtw = ws + 16777216;         // [bh][d][s]
    ushort_t* Aow = ws + 20971520;         // [b][s][1024]

    cvt_kernel<<<4096, 256, 0, stream>>>(x, Wq, Wk, Wv, Wo, ws);
    gemm_bt<<<dim3(24, 32), 512, 0, stream>>>(xb, wqb, Qw, Kw, Vtw, nullptr, 0);
    attn_kernel<<<dim3(32, 16), 512, 0, stream>>>(Qw, Kw, Vtw, Aow);
    gemm_bt<<<dim3(8, 32), 512, 0, stream>>>(Aow, wob, nullptr, nullptr, nullptr,
                                             (float*)d_out, 1);
}